// Round 3
// baseline (7003.388 us; speedup 1.0000x reference)
//
#include <hip/hip_runtime.h>

typedef unsigned short u16;
typedef __bf16 bf16x8 __attribute__((ext_vector_type(8)));
typedef float f32x4 __attribute__((ext_vector_type(4)));

static __device__ __forceinline__ float bf2f(u16 u) {
    union { unsigned int i; float f; } v; v.i = ((unsigned int)u) << 16; return v.f;
}
static __device__ __forceinline__ u16 f2bf(float f) {
    union { float f; unsigned int i; } v; v.f = f;
    unsigned int b = v.i;
    b += 0x7fffu + ((b >> 16) & 1u);   // RNE
    return (u16)(b >> 16);
}
// external-input accessors: isf32 selects fp32 vs bf16 interpretation (wave-uniform)
static __device__ __forceinline__ u16 ldbf(const void* p, size_t i, int isf32) {
    return isf32 ? f2bf(((const float*)p)[i]) : ((const u16*)p)[i];
}
static __device__ __forceinline__ float ldf(const void* p, size_t i, int isf32) {
    return isf32 ? ((const float*)p)[i] : bf2f(((const u16*)p)[i]);
}

// ---------------- dtype detector ----------------
// fp32 buffer: u16 at even index = float mantissa-low bits -> uniform exponent, ~18% "sane".
// bf16 buffer: every u16 is ~N(0,1) -> ~100% sane. flag=1 means fp32.
__global__ __launch_bounds__(256) void k_detect(const u16* __restrict__ xu, int* __restrict__ flag) {
    u16 v = xu[threadIdx.x * 2];
    int e = (v >> 7) & 0xFF;
    int sane = (e >= 87 && e <= 133) ? 1 : 0;
    int total = __syncthreads_count(sane);
    if (threadIdx.x == 0) flag[0] = (total < 192) ? 1 : 0;
}

// ---------------- x -> f32 residual stream ----------------
__global__ __launch_bounds__(256) void k_b2f(const void* __restrict__ in, float* __restrict__ out, int n,
                                             const int* __restrict__ flagp) {
    int isf32 = *flagp;
    int i = blockIdx.x * 256 + threadIdx.x;
    if (i < n) out[i] = ldf(in, i, isf32);
}

// ---------------- LayerNorm: fp32 in -> bf16 out ----------------
__global__ __launch_bounds__(256) void k_layernorm(const float* __restrict__ X, const void* __restrict__ G,
                                                   const void* __restrict__ Bb, u16* __restrict__ Y, int D,
                                                   const int* __restrict__ flagp) {
    int isf32 = *flagp;
    int row = blockIdx.x;
    const float* xr = X + (size_t)row * D;
    float s = 0.f, s2 = 0.f;
    for (int i = threadIdx.x; i < D; i += 256) { float v = xr[i]; s += v; s2 += v * v; }
    #pragma unroll
    for (int off = 32; off; off >>= 1) { s += __shfl_down(s, off); s2 += __shfl_down(s2, off); }
    __shared__ float rs[4], rs2[4];
    __shared__ float stat[2];
    int w = threadIdx.x >> 6;
    if ((threadIdx.x & 63) == 0) { rs[w] = s; rs2[w] = s2; }
    __syncthreads();
    if (threadIdx.x == 0) {
        float ts = rs[0] + rs[1] + rs[2] + rs[3];
        float ts2 = rs2[0] + rs2[1] + rs2[2] + rs2[3];
        float mu = ts / D;
        float var = ts2 / D - mu * mu;
        stat[0] = mu; stat[1] = rsqrtf(var + 1e-5f);
    }
    __syncthreads();
    float mu = stat[0], rstd = stat[1];
    u16* yr = Y + (size_t)row * D;
    for (int i = threadIdx.x; i < D; i += 256) {
        yr[i] = f2bf((xr[i] - mu) * rstd * ldf(G, i, isf32) + ldf(Bb, i, isf32));
    }
}

// ---------------- bf16 MFMA GEMM: C[M,N] = A[M,K] @ B[K,N] ----------------
// A: internal bf16 unless AEXT (then external, flag-typed). B/bias: external flag-typed.
// EPI: 0 = store bf16 C; 2 = Rf += acc + bias (fp32 residual in-place);
//      3 = ((float*)Cout) = acc + bias + Rf   (fp32 final output)
template <int EPI, bool AEXT>
__global__ __launch_bounds__(256) void k_gemm(const void* __restrict__ A, const void* __restrict__ B,
                                              void* __restrict__ Cout, float* __restrict__ Rf,
                                              const void* __restrict__ bias,
                                              int M, int N, int K, const int* __restrict__ flagp) {
    int isf32 = *flagp;
    __shared__ u16 As[64][40];   // [m][k]
    __shared__ u16 Bs[64][40];   // [n][k] (transposed at stage-in)
    int tid = threadIdx.x;
    int row0 = blockIdx.x * 64, col0 = blockIdx.y * 64;
    int wave = tid >> 6, lane = tid & 63;
    int wm = (wave >> 1) * 32, wn = (wave & 1) * 32;
    int quad = lane >> 4, r = lane & 15;
    int arow = tid >> 2, akk = (tid & 3) * 8;   // A stage: 64 rows x 4 chunks of 8
    int bnl = tid & 63, bkk = (tid >> 6) * 8;   // B stage: 64 cols x 4 chunks of 8 k
    int garow = row0 + arow;
    f32x4 acc[2][2] = {};
    for (int k0 = 0; k0 < K; k0 += 32) {
        uint4 aval = {0u, 0u, 0u, 0u};
        if (garow < M) {
            if (AEXT && isf32) {
                const float* Af = (const float*)A;
                u16 t[8];
                #pragma unroll
                for (int j = 0; j < 8; ++j) t[j] = f2bf(Af[(size_t)garow * K + k0 + akk + j]);
                aval = *(uint4*)t;
            } else {
                aval = *(const uint4*)((const u16*)A + (size_t)garow * K + k0 + akk);
            }
        }
        u16 btmp[8];
        #pragma unroll
        for (int j = 0; j < 8; ++j) btmp[j] = ldbf(B, (size_t)(k0 + bkk + j) * N + col0 + bnl, isf32);
        __syncthreads();
        *(uint4*)(&As[arow][akk]) = aval;
        *(uint4*)(&Bs[bnl][bkk]) = *(uint4*)btmp;
        __syncthreads();
        bf16x8 a0 = *(const bf16x8*)(&As[wm + r][quad * 8]);
        bf16x8 a1 = *(const bf16x8*)(&As[wm + 16 + r][quad * 8]);
        bf16x8 b0 = *(const bf16x8*)(&Bs[wn + r][quad * 8]);
        bf16x8 b1 = *(const bf16x8*)(&Bs[wn + 16 + r][quad * 8]);
        acc[0][0] = __builtin_amdgcn_mfma_f32_16x16x32_bf16(a0, b0, acc[0][0], 0, 0, 0);
        acc[0][1] = __builtin_amdgcn_mfma_f32_16x16x32_bf16(a0, b1, acc[0][1], 0, 0, 0);
        acc[1][0] = __builtin_amdgcn_mfma_f32_16x16x32_bf16(a1, b0, acc[1][0], 0, 0, 0);
        acc[1][1] = __builtin_amdgcn_mfma_f32_16x16x32_bf16(a1, b1, acc[1][1], 0, 0, 0);
    }
    #pragma unroll
    for (int i = 0; i < 2; ++i)
        #pragma unroll
        for (int jn = 0; jn < 2; ++jn)
            #pragma unroll
            for (int t = 0; t < 4; ++t) {
                int grow = row0 + wm + i * 16 + quad * 4 + t;
                int gcol = col0 + wn + jn * 16 + r;
                if (grow >= M) continue;
                float v = acc[i][jn][t];
                size_t off = (size_t)grow * N + gcol;
                if (EPI == 0) {
                    ((u16*)Cout)[off] = f2bf(v);
                } else if (EPI == 2) {
                    Rf[off] += v + ldf(bias, gcol, isf32);
                } else {
                    ((float*)Cout)[off] = v + ldf(bias, gcol, isf32) + Rf[off];
                }
            }
}

// ---------------- ff1 GEMM with fused GEGLU ----------------
__global__ __launch_bounds__(256) void k_gemm_geglu(const u16* __restrict__ A, const void* __restrict__ B,
                                                    const void* __restrict__ bias, u16* __restrict__ Out,
                                                    int M, int Nout, int K, int ldb,
                                                    const int* __restrict__ flagp) {
    int isf32 = *flagp;
    __shared__ u16 As[64][40];
    __shared__ u16 Bs[64][40];
    int tid = threadIdx.x;
    int row0 = blockIdx.x * 64, col0 = blockIdx.y * 64;
    int wave = tid >> 6, lane = tid & 63;
    int wm = (wave >> 1) * 32, wn = (wave & 1) * 32;
    int quad = lane >> 4, r = lane & 15;
    int arow = tid >> 2, akk = (tid & 3) * 8;
    int bnl = tid & 63, bkk = (tid >> 6) * 8;
    int garow = row0 + arow;
    f32x4 acc[2][2][2] = {};
    for (int p = 0; p < 2; ++p) {
        for (int k0 = 0; k0 < K; k0 += 32) {
            uint4 aval = {0u, 0u, 0u, 0u};
            if (garow < M) aval = *(const uint4*)(A + (size_t)garow * K + k0 + akk);
            u16 btmp[8];
            #pragma unroll
            for (int j = 0; j < 8; ++j)
                btmp[j] = ldbf(B, (size_t)(k0 + bkk + j) * ldb + p * Nout + col0 + bnl, isf32);
            __syncthreads();
            *(uint4*)(&As[arow][akk]) = aval;
            *(uint4*)(&Bs[bnl][bkk]) = *(uint4*)btmp;
            __syncthreads();
            bf16x8 a0 = *(const bf16x8*)(&As[wm + r][quad * 8]);
            bf16x8 a1 = *(const bf16x8*)(&As[wm + 16 + r][quad * 8]);
            bf16x8 b0 = *(const bf16x8*)(&Bs[wn + r][quad * 8]);
            bf16x8 b1 = *(const bf16x8*)(&Bs[wn + 16 + r][quad * 8]);
            acc[p][0][0] = __builtin_amdgcn_mfma_f32_16x16x32_bf16(a0, b0, acc[p][0][0], 0, 0, 0);
            acc[p][0][1] = __builtin_amdgcn_mfma_f32_16x16x32_bf16(a0, b1, acc[p][0][1], 0, 0, 0);
            acc[p][1][0] = __builtin_amdgcn_mfma_f32_16x16x32_bf16(a1, b0, acc[p][1][0], 0, 0, 0);
            acc[p][1][1] = __builtin_amdgcn_mfma_f32_16x16x32_bf16(a1, b1, acc[p][1][1], 0, 0, 0);
        }
    }
    #pragma unroll
    for (int i = 0; i < 2; ++i)
        #pragma unroll
        for (int jn = 0; jn < 2; ++jn)
            #pragma unroll
            for (int t = 0; t < 4; ++t) {
                int grow = row0 + wm + i * 16 + quad * 4 + t;
                int gcol = col0 + wn + jn * 16 + r;
                if (grow >= M) continue;
                float a = acc[0][i][jn][t] + ldf(bias, gcol, isf32);
                float u = acc[1][i][jn][t] + ldf(bias, Nout + gcol, isf32);
                float th = tanhf(0.7978845608f * (u + 0.044715f * u * u * u));
                float gl = 0.5f * u * (1.f + th);
                Out[(size_t)grow * Nout + gcol] = f2bf(a * gl);
            }
}

// ---------------- attention: softmax(QK^T * 0.125) V ----------------
#define QROWS 8
__global__ __launch_bounds__(256) void k_attention(const u16* __restrict__ Q, const u16* __restrict__ Kp,
                                                   const u16* __restrict__ Vp, u16* __restrict__ O,
                                                   int N, int Mkv, int H) {
    __shared__ float S[QROWS][1025];
    __shared__ float Qs[QROWS][64];
    __shared__ float rowsum[QROWS];
    const int ld = 1280;
    int nt = N / QROWS;
    int qt = blockIdx.x % nt;
    int bh = blockIdx.x / nt;
    int h = bh % H, b = bh / H;
    int tid = threadIdx.x;
    const u16* qb = Q + ((size_t)(b * N + qt * QROWS)) * ld + h * 64;
    for (int idx = tid; idx < QROWS * 64; idx += 256) {
        int i = idx >> 6, d = idx & 63;
        Qs[i][d] = bf2f(qb[(size_t)i * ld + d]) * 0.125f;
    }
    __syncthreads();
    const u16* kb = Kp + ((size_t)b * Mkv) * ld + h * 64;
    for (int i = 0; i < QROWS; ++i) {
        for (int m = tid; m < Mkv; m += 256) {
            const u16* kr = kb + (size_t)m * ld;
            float acc = 0.f;
            #pragma unroll
            for (int d = 0; d < 64; d += 4) {
                ushort4 kk = *(const ushort4*)(kr + d);
                acc += Qs[i][d] * bf2f(kk.x);
                acc += Qs[i][d + 1] * bf2f(kk.y);
                acc += Qs[i][d + 2] * bf2f(kk.z);
                acc += Qs[i][d + 3] * bf2f(kk.w);
            }
            S[i][m] = acc;
        }
    }
    __syncthreads();
    {
        int i = tid >> 5, j = tid & 31;
        float mx = -1e30f;
        for (int m = j; m < Mkv; m += 32) mx = fmaxf(mx, S[i][m]);
        #pragma unroll
        for (int off = 16; off; off >>= 1) mx = fmaxf(mx, __shfl_xor(mx, off));
        float sm = 0.f;
        for (int m = j; m < Mkv; m += 32) { float e = __expf(S[i][m] - mx); S[i][m] = e; sm += e; }
        #pragma unroll
        for (int off = 16; off; off >>= 1) sm += __shfl_xor(sm, off);
        if (j == 0) rowsum[i] = sm;
    }
    __syncthreads();
    {
        int d = tid & 63, w = tid >> 6;
        const u16* vb = Vp + ((size_t)b * Mkv) * ld + h * 64 + d;
        float acc0 = 0.f, acc1 = 0.f;
        for (int m = 0; m < Mkv; ++m) {
            float vv = bf2f(vb[(size_t)m * ld]);
            acc0 += S[w][m] * vv;
            acc1 += S[w + 4][m] * vv;
        }
        u16* ob = O + ((size_t)(b * N + qt * QROWS)) * ld + h * 64 + d;
        ob[(size_t)w * ld] = f2bf(acc0 / rowsum[w]);
        ob[(size_t)(w + 4) * ld] = f2bf(acc1 / rowsum[w + 4]);
    }
}

extern "C" void kernel_launch(void* const* d_in, const int* in_sizes, int n_in,
                              void* d_out, int out_size, void* d_ws, size_t ws_size,
                              hipStream_t stream) {
    const void* x    = d_in[0];
    const void* ctx  = d_in[1];
    const void* g1   = d_in[2];
    const void* be1  = d_in[3];
    const void* wq1  = d_in[4];
    const void* wk1  = d_in[5];
    const void* wv1  = d_in[6];
    const void* wo1  = d_in[7];
    const void* bo1  = d_in[8];
    const void* g2   = d_in[9];
    const void* be2  = d_in[10];
    const void* wq2  = d_in[11];
    const void* wk2  = d_in[12];
    const void* wv2  = d_in[13];
    const void* wo2  = d_in[14];
    const void* bo2  = d_in[15];
    const void* g3   = d_in[16];
    const void* be3  = d_in[17];
    const void* wff1 = d_in[18];
    const void* bff1 = d_in[19];
    const void* wff2 = d_in[20];
    const void* bff2 = d_in[21];

    // workspace layout (bytes); peak 74,977,536 (~71.5 MiB)
    char* ws = (char*)d_ws;
    int*   flag    = (int*)(ws);                 // [0,256)
    float* xres    = (float*)(ws + 256);         // 4096x1280 f32
    u16* lnout     = (u16*)(ws + 20971776);      // 4096x1280 bf16
    u16* q         = (u16*)(ws + 31457536);
    u16* kbuf      = (u16*)(ws + 41943296);
    u16* vbuf      = (u16*)(ws + 52429056);
    u16* attnout   = (u16*)(ws + 62914816);
    u16* k2        = (u16*)(ws + 73400576);      // 308x1280 bf16
    u16* v2        = (u16*)(ws + 74189056);      // ends 74977536
    u16* gbuf      = (u16*)(ws + 31457536);      // 4096x5120 bf16, aliases q..attnout (dead by then)

    const int BT = 4096, D = 1280;
    dim3 blk(256);
    dim3 g_gemm(64, 20);
    dim3 g_kv(5, 20);

    k_detect<<<dim3(1), blk, 0, stream>>>((const u16*)x, flag);
    k_b2f<<<dim3((BT * D + 255) / 256), blk, 0, stream>>>(x, xres, BT * D, flag);
    // --- self attention ---
    k_layernorm<<<dim3(BT), blk, 0, stream>>>(xres, g1, be1, lnout, D, flag);
    k_gemm<0, false><<<g_gemm, blk, 0, stream>>>(lnout, wq1, q, nullptr, nullptr, BT, D, D, flag);
    k_gemm<0, false><<<g_gemm, blk, 0, stream>>>(lnout, wk1, kbuf, nullptr, nullptr, BT, D, D, flag);
    k_gemm<0, false><<<g_gemm, blk, 0, stream>>>(lnout, wv1, vbuf, nullptr, nullptr, BT, D, D, flag);
    k_attention<<<dim3(4 * 20 * 128), blk, 0, stream>>>(q, kbuf, vbuf, attnout, 1024, 1024, 20);
    k_gemm<2, false><<<g_gemm, blk, 0, stream>>>(attnout, wo1, nullptr, xres, bo1, BT, D, D, flag);
    // --- cross attention ---
    k_layernorm<<<dim3(BT), blk, 0, stream>>>(xres, g2, be2, lnout, D, flag);
    k_gemm<0, false><<<g_gemm, blk, 0, stream>>>(lnout, wq2, q, nullptr, nullptr, BT, D, D, flag);
    k_gemm<0, true><<<g_kv, blk, 0, stream>>>(ctx, wk2, k2, nullptr, nullptr, 308, D, 768, flag);
    k_gemm<0, true><<<g_kv, blk, 0, stream>>>(ctx, wv2, v2, nullptr, nullptr, 308, D, 768, flag);
    k_attention<<<dim3(4 * 20 * 128), blk, 0, stream>>>(q, k2, v2, attnout, 1024, 77, 20);
    k_gemm<2, false><<<g_gemm, blk, 0, stream>>>(attnout, wo2, nullptr, xres, bo2, BT, D, D, flag);
    // --- GEGLU FF ---
    k_layernorm<<<dim3(BT), blk, 0, stream>>>(xres, g3, be3, lnout, D, flag);
    k_gemm_geglu<<<dim3(64, 80), blk, 0, stream>>>(lnout, wff1, bff1, gbuf, BT, 5120, D, 10240, flag);
    k_gemm<3, false><<<g_gemm, blk, 0, stream>>>(gbuf, wff2, d_out, xres, bff2, BT, D, 5120, flag);
}

// Round 4
// 3173.825 us; speedup vs baseline: 2.2066x; 2.2066x over previous
//
#include <hip/hip_runtime.h>

typedef unsigned short u16;
typedef __bf16 bf16x8 __attribute__((ext_vector_type(8)));
typedef float f32x4 __attribute__((ext_vector_type(4)));

static __device__ __forceinline__ float bf2f(u16 u) {
    union { unsigned int i; float f; } v; v.i = ((unsigned int)u) << 16; return v.f;
}
static __device__ __forceinline__ u16 f2bf(float f) {
    union { float f; unsigned int i; } v; v.f = f;
    unsigned int b = v.i;
    b += 0x7fffu + ((b >> 16) & 1u);   // RNE
    return (u16)(b >> 16);
}
// external-input accessors: isf32 selects fp32 vs bf16 interpretation (wave-uniform)
static __device__ __forceinline__ u16 ldbf(const void* p, size_t i, int isf32) {
    return isf32 ? f2bf(((const float*)p)[i]) : ((const u16*)p)[i];
}
static __device__ __forceinline__ float ldf(const void* p, size_t i, int isf32) {
    return isf32 ? ((const float*)p)[i] : bf2f(((const u16*)p)[i]);
}

// ---------------- dtype detector (insurance; inputs measured fp32) ----------------
__global__ __launch_bounds__(256) void k_detect(const u16* __restrict__ xu, int* __restrict__ flag) {
    u16 v = xu[threadIdx.x * 2];
    int e = (v >> 7) & 0xFF;
    int sane = (e >= 87 && e <= 133) ? 1 : 0;
    int total = __syncthreads_count(sane);
    if (threadIdx.x == 0) flag[0] = (total < 192) ? 1 : 0;
}

// ---------------- x -> f32 residual stream ----------------
__global__ __launch_bounds__(256) void k_b2f(const void* __restrict__ in, float* __restrict__ out, int n,
                                             const int* __restrict__ flagp) {
    int isf32 = *flagp;
    int i = blockIdx.x * 256 + threadIdx.x;
    if (i < n) out[i] = ldf(in, i, isf32);
}

// ---------------- LayerNorm: fp32 in -> bf16 out ----------------
__global__ __launch_bounds__(256) void k_layernorm(const float* __restrict__ X, const void* __restrict__ G,
                                                   const void* __restrict__ Bb, u16* __restrict__ Y, int D,
                                                   const int* __restrict__ flagp) {
    int isf32 = *flagp;
    int row = blockIdx.x;
    const float* xr = X + (size_t)row * D;
    float s = 0.f, s2 = 0.f;
    for (int i = threadIdx.x; i < D; i += 256) { float v = xr[i]; s += v; s2 += v * v; }
    #pragma unroll
    for (int off = 32; off; off >>= 1) { s += __shfl_down(s, off); s2 += __shfl_down(s2, off); }
    __shared__ float rs[4], rs2[4];
    __shared__ float stat[2];
    int w = threadIdx.x >> 6;
    if ((threadIdx.x & 63) == 0) { rs[w] = s; rs2[w] = s2; }
    __syncthreads();
    if (threadIdx.x == 0) {
        float ts = rs[0] + rs[1] + rs[2] + rs[3];
        float ts2 = rs2[0] + rs2[1] + rs2[2] + rs2[3];
        float mu = ts / D;
        float var = ts2 / D - mu * mu;
        stat[0] = mu; stat[1] = rsqrtf(var + 1e-5f);
    }
    __syncthreads();
    float mu = stat[0], rstd = stat[1];
    u16* yr = Y + (size_t)row * D;
    for (int i = threadIdx.x; i < D; i += 256) {
        yr[i] = f2bf((xr[i] - mu) * rstd * ldf(G, i, isf32) + ldf(Bb, i, isf32));
    }
}

// ---------------- bf16 MFMA GEMM: C[M,N] = A[M,K] @ B[K,N] ----------------
// EPI: 0 = store bf16 C; 2 = Rf += acc + bias (fp32 residual in-place);
//      3 = ((float*)Cout) = acc + bias + Rf   (fp32 final output)
template <int EPI, bool AEXT>
__global__ __launch_bounds__(256) void k_gemm(const void* __restrict__ A, const void* __restrict__ B,
                                              void* __restrict__ Cout, float* __restrict__ Rf,
                                              const void* __restrict__ bias,
                                              int M, int N, int K, const int* __restrict__ flagp) {
    int isf32 = *flagp;
    __shared__ u16 As[64][40];   // [m][k]
    __shared__ u16 Bs[64][40];   // [n][k] (transposed at stage-in)
    int tid = threadIdx.x;
    int row0 = blockIdx.x * 64, col0 = blockIdx.y * 64;
    int wave = tid >> 6, lane = tid & 63;
    int wm = (wave >> 1) * 32, wn = (wave & 1) * 32;
    int quad = lane >> 4, r = lane & 15;
    int arow = tid >> 2, akk = (tid & 3) * 8;
    int bnl = tid & 63, bkk = (tid >> 6) * 8;
    int garow = row0 + arow;
    f32x4 acc[2][2] = {};
    for (int k0 = 0; k0 < K; k0 += 32) {
        uint4 aval = {0u, 0u, 0u, 0u};
        if (garow < M) {
            if (AEXT && isf32) {
                const float* Af = (const float*)A;
                u16 t[8];
                #pragma unroll
                for (int j = 0; j < 8; ++j) t[j] = f2bf(Af[(size_t)garow * K + k0 + akk + j]);
                aval = *(uint4*)t;
            } else {
                aval = *(const uint4*)((const u16*)A + (size_t)garow * K + k0 + akk);
            }
        }
        u16 btmp[8];
        #pragma unroll
        for (int j = 0; j < 8; ++j) btmp[j] = ldbf(B, (size_t)(k0 + bkk + j) * N + col0 + bnl, isf32);
        __syncthreads();
        *(uint4*)(&As[arow][akk]) = aval;
        *(uint4*)(&Bs[bnl][bkk]) = *(uint4*)btmp;
        __syncthreads();
        bf16x8 a0 = *(const bf16x8*)(&As[wm + r][quad * 8]);
        bf16x8 a1 = *(const bf16x8*)(&As[wm + 16 + r][quad * 8]);
        bf16x8 b0 = *(const bf16x8*)(&Bs[wn + r][quad * 8]);
        bf16x8 b1 = *(const bf16x8*)(&Bs[wn + 16 + r][quad * 8]);
        acc[0][0] = __builtin_amdgcn_mfma_f32_16x16x32_bf16(a0, b0, acc[0][0], 0, 0, 0);
        acc[0][1] = __builtin_amdgcn_mfma_f32_16x16x32_bf16(a0, b1, acc[0][1], 0, 0, 0);
        acc[1][0] = __builtin_amdgcn_mfma_f32_16x16x32_bf16(a1, b0, acc[1][0], 0, 0, 0);
        acc[1][1] = __builtin_amdgcn_mfma_f32_16x16x32_bf16(a1, b1, acc[1][1], 0, 0, 0);
    }
    #pragma unroll
    for (int i = 0; i < 2; ++i)
        #pragma unroll
        for (int jn = 0; jn < 2; ++jn)
            #pragma unroll
            for (int t = 0; t < 4; ++t) {
                int grow = row0 + wm + i * 16 + quad * 4 + t;
                int gcol = col0 + wn + jn * 16 + r;
                if (grow >= M) continue;
                float v = acc[i][jn][t];
                size_t off = (size_t)grow * N + gcol;
                if (EPI == 0) {
                    ((u16*)Cout)[off] = f2bf(v);
                } else if (EPI == 2) {
                    Rf[off] += v + ldf(bias, gcol, isf32);
                } else {
                    ((float*)Cout)[off] = v + ldf(bias, gcol, isf32) + Rf[off];
                }
            }
}

// ---------------- ff1 GEMM with fused GEGLU ----------------
__global__ __launch_bounds__(256) void k_gemm_geglu(const u16* __restrict__ A, const void* __restrict__ B,
                                                    const void* __restrict__ bias, u16* __restrict__ Out,
                                                    int M, int Nout, int K, int ldb,
                                                    const int* __restrict__ flagp) {
    int isf32 = *flagp;
    __shared__ u16 As[64][40];
    __shared__ u16 Bs[64][40];
    int tid = threadIdx.x;
    int row0 = blockIdx.x * 64, col0 = blockIdx.y * 64;
    int wave = tid >> 6, lane = tid & 63;
    int wm = (wave >> 1) * 32, wn = (wave & 1) * 32;
    int quad = lane >> 4, r = lane & 15;
    int arow = tid >> 2, akk = (tid & 3) * 8;
    int bnl = tid & 63, bkk = (tid >> 6) * 8;
    int garow = row0 + arow;
    f32x4 acc[2][2][2] = {};
    for (int p = 0; p < 2; ++p) {
        for (int k0 = 0; k0 < K; k0 += 32) {
            uint4 aval = {0u, 0u, 0u, 0u};
            if (garow < M) aval = *(const uint4*)(A + (size_t)garow * K + k0 + akk);
            u16 btmp[8];
            #pragma unroll
            for (int j = 0; j < 8; ++j)
                btmp[j] = ldbf(B, (size_t)(k0 + bkk + j) * ldb + p * Nout + col0 + bnl, isf32);
            __syncthreads();
            *(uint4*)(&As[arow][akk]) = aval;
            *(uint4*)(&Bs[bnl][bkk]) = *(uint4*)btmp;
            __syncthreads();
            bf16x8 a0 = *(const bf16x8*)(&As[wm + r][quad * 8]);
            bf16x8 a1 = *(const bf16x8*)(&As[wm + 16 + r][quad * 8]);
            bf16x8 b0 = *(const bf16x8*)(&Bs[wn + r][quad * 8]);
            bf16x8 b1 = *(const bf16x8*)(&Bs[wn + 16 + r][quad * 8]);
            acc[p][0][0] = __builtin_amdgcn_mfma_f32_16x16x32_bf16(a0, b0, acc[p][0][0], 0, 0, 0);
            acc[p][0][1] = __builtin_amdgcn_mfma_f32_16x16x32_bf16(a0, b1, acc[p][0][1], 0, 0, 0);
            acc[p][1][0] = __builtin_amdgcn_mfma_f32_16x16x32_bf16(a1, b0, acc[p][1][0], 0, 0, 0);
            acc[p][1][1] = __builtin_amdgcn_mfma_f32_16x16x32_bf16(a1, b1, acc[p][1][1], 0, 0, 0);
        }
    }
    #pragma unroll
    for (int i = 0; i < 2; ++i)
        #pragma unroll
        for (int jn = 0; jn < 2; ++jn)
            #pragma unroll
            for (int t = 0; t < 4; ++t) {
                int grow = row0 + wm + i * 16 + quad * 4 + t;
                int gcol = col0 + wn + jn * 16 + r;
                if (grow >= M) continue;
                float a = acc[0][i][jn][t] + ldf(bias, gcol, isf32);
                float u = acc[1][i][jn][t] + ldf(bias, Nout + gcol, isf32);
                float th = tanhf(0.7978845608f * (u + 0.044715f * u * u * u));
                float gl = 0.5f * u * (1.f + th);
                Out[(size_t)grow * Nout + gcol] = f2bf(a * gl);
            }
}

// ---------------- MFMA flash attention: O = softmax(Q K^T * 0.125) V ----------------
// Head-interleaved layout: row (b*N+n)*1280 + h*64 for Q/O; (b*Mkv+m)*1280 + h*64 for K/V.
// Wave = 16 Q rows; block = 64 Q rows; KV tiles of 32 with online softmax.
// Fragment maps (m89/m91): A[m=lane&15][k=quad*8+j]; B[k=quad*8+j][n=lane&15];
// C/D: row=quad*4+reg, col=lane&15.
__global__ __launch_bounds__(256) void k_attn_flash(const u16* __restrict__ Q, const u16* __restrict__ K,
                                                    const u16* __restrict__ V, u16* __restrict__ O,
                                                    int N, int Mkv, int H) {
    __shared__ u16 Sp[4][16][40];   // per-wave P tile (q-row x kv), 80B rows (16B aligned)
    __shared__ u16 VT[64][40];      // block-shared V^T tile: [d][kv]
    const int ld = 1280;
    int nt = N / 64;
    int qt = blockIdx.x % nt;
    int bh = blockIdx.x / nt;
    int h = bh % H, b = bh / H;
    int tid = threadIdx.x, wave = tid >> 6, lane = tid & 63;
    int quad = lane >> 4, r = lane & 15;
    int q0 = qt * 64 + wave * 16;

    const u16* qbase = Q + ((size_t)(b * N + q0 + r)) * ld + h * 64;
    bf16x8 aq0 = *(const bf16x8*)(qbase + quad * 8);        // k chunk 0 (d 0..31)
    bf16x8 aq1 = *(const bf16x8*)(qbase + 32 + quad * 8);   // k chunk 1 (d 32..63)

    f32x4 accO[4] = {};              // n-groups g: cols d = g*16 + r
    float m_i[4] = {-1e30f, -1e30f, -1e30f, -1e30f};
    float l_i[4] = {0.f, 0.f, 0.f, 0.f};

    int vkv = tid & 31, vdg = tid >> 5;   // V stage: kv row offset, d-group of 8

    for (int kv0 = 0; kv0 < Mkv; kv0 += 32) {
        // K fragments (B operand of QK^T): direct 16B global loads, row-clamped
        int kr0 = min(kv0 + r, Mkv - 1);
        int kr1 = min(kv0 + 16 + r, Mkv - 1);
        const u16* kb0 = K + ((size_t)(b * Mkv + kr0)) * ld + h * 64;
        const u16* kb1 = K + ((size_t)(b * Mkv + kr1)) * ld + h * 64;
        bf16x8 bk00 = *(const bf16x8*)(kb0 + quad * 8);
        bf16x8 bk01 = *(const bf16x8*)(kb0 + 32 + quad * 8);
        bf16x8 bk10 = *(const bf16x8*)(kb1 + quad * 8);
        bf16x8 bk11 = *(const bf16x8*)(kb1 + 32 + quad * 8);
        // V tile chunk for transposed staging (16B per thread), row-clamped
        int vrow = min(kv0 + vkv, Mkv - 1);
        uint4 vv = *(const uint4*)(V + ((size_t)(b * Mkv + vrow)) * ld + h * 64 + vdg * 8);

        __syncthreads();   // previous tile's VT fully consumed
        VT[vdg * 8 + 0][vkv] = (u16)(vv.x);
        VT[vdg * 8 + 1][vkv] = (u16)(vv.x >> 16);
        VT[vdg * 8 + 2][vkv] = (u16)(vv.y);
        VT[vdg * 8 + 3][vkv] = (u16)(vv.y >> 16);
        VT[vdg * 8 + 4][vkv] = (u16)(vv.z);
        VT[vdg * 8 + 5][vkv] = (u16)(vv.z >> 16);
        VT[vdg * 8 + 6][vkv] = (u16)(vv.w);
        VT[vdg * 8 + 7][vkv] = (u16)(vv.w >> 16);
        __syncthreads();

        // QK^T: two 16-col halves, K-dim 64 = 2 chained MFMAs each
        f32x4 s0 = {}, s1 = {};
        s0 = __builtin_amdgcn_mfma_f32_16x16x32_bf16(aq0, bk00, s0, 0, 0, 0);
        s0 = __builtin_amdgcn_mfma_f32_16x16x32_bf16(aq1, bk01, s0, 0, 0, 0);
        s1 = __builtin_amdgcn_mfma_f32_16x16x32_bf16(aq0, bk10, s1, 0, 0, 0);
        s1 = __builtin_amdgcn_mfma_f32_16x16x32_bf16(aq1, bk11, s1, 0, 0, 0);
        bool mask0 = (kv0 + r) >= Mkv;
        bool mask1 = (kv0 + 16 + r) >= Mkv;

        // online softmax per q-row (row = quad*4 + t); stats across 16-lane quad group
        #pragma unroll
        for (int t = 0; t < 4; ++t) {
            float a = mask0 ? -1e30f : s0[t] * 0.125f;
            float c = mask1 ? -1e30f : s1[t] * 0.125f;
            float mx = fmaxf(a, c);
            mx = fmaxf(mx, __shfl_xor(mx, 1));
            mx = fmaxf(mx, __shfl_xor(mx, 2));
            mx = fmaxf(mx, __shfl_xor(mx, 4));
            mx = fmaxf(mx, __shfl_xor(mx, 8));
            float mn = fmaxf(m_i[t], mx);
            float alpha = __expf(m_i[t] - mn);
            float p0 = __expf(a - mn);
            float p1 = __expf(c - mn);
            float ps = p0 + p1;
            ps += __shfl_xor(ps, 1);
            ps += __shfl_xor(ps, 2);
            ps += __shfl_xor(ps, 4);
            ps += __shfl_xor(ps, 8);
            l_i[t] = l_i[t] * alpha + ps;
            m_i[t] = mn;
            accO[0][t] *= alpha; accO[1][t] *= alpha; accO[2][t] *= alpha; accO[3][t] *= alpha;
            Sp[wave][quad * 4 + t][r] = f2bf(p0);
            Sp[wave][quad * 4 + t][16 + r] = f2bf(p1);
        }

        // PV: A = P (q-row x kv, K=32), B = V^T rows
        bf16x8 ap = *(const bf16x8*)(&Sp[wave][r][quad * 8]);
        #pragma unroll
        for (int g = 0; g < 4; ++g) {
            bf16x8 bv = *(const bf16x8*)(&VT[g * 16 + r][quad * 8]);
            accO[g] = __builtin_amdgcn_mfma_f32_16x16x32_bf16(ap, bv, accO[g], 0, 0, 0);
        }
    }

    u16* ob = O + ((size_t)(b * N + q0)) * ld + h * 64;
    #pragma unroll
    for (int t = 0; t < 4; ++t) {
        float inv = 1.f / l_i[t];
        #pragma unroll
        for (int g = 0; g < 4; ++g)
            ob[(size_t)(quad * 4 + t) * ld + g * 16 + r] = f2bf(accO[g][t] * inv);
    }
}

extern "C" void kernel_launch(void* const* d_in, const int* in_sizes, int n_in,
                              void* d_out, int out_size, void* d_ws, size_t ws_size,
                              hipStream_t stream) {
    const void* x    = d_in[0];
    const void* ctx  = d_in[1];
    const void* g1   = d_in[2];
    const void* be1  = d_in[3];
    const void* wq1  = d_in[4];
    const void* wk1  = d_in[5];
    const void* wv1  = d_in[6];
    const void* wo1  = d_in[7];
    const void* bo1  = d_in[8];
    const void* g2   = d_in[9];
    const void* be2  = d_in[10];
    const void* wq2  = d_in[11];
    const void* wk2  = d_in[12];
    const void* wv2  = d_in[13];
    const void* wo2  = d_in[14];
    const void* bo2  = d_in[15];
    const void* g3   = d_in[16];
    const void* be3  = d_in[17];
    const void* wff1 = d_in[18];
    const void* bff1 = d_in[19];
    const void* wff2 = d_in[20];
    const void* bff2 = d_in[21];

    // workspace layout (bytes); peak 74,977,536 (~71.5 MiB)
    char* ws = (char*)d_ws;
    int*   flag    = (int*)(ws);                 // [0,256)
    float* xres    = (float*)(ws + 256);         // 4096x1280 f32
    u16* lnout     = (u16*)(ws + 20971776);      // 4096x1280 bf16
    u16* q         = (u16*)(ws + 31457536);
    u16* kbuf      = (u16*)(ws + 41943296);
    u16* vbuf      = (u16*)(ws + 52429056);
    u16* attnout   = (u16*)(ws + 62914816);
    u16* k2        = (u16*)(ws + 73400576);      // 308x1280 bf16
    u16* v2        = (u16*)(ws + 74189056);      // ends 74977536
    u16* gbuf      = (u16*)(ws + 31457536);      // 4096x5120 bf16, aliases q..attnout (dead by then)

    const int BT = 4096, D = 1280;
    dim3 blk(256);
    dim3 g_gemm(64, 20);
    dim3 g_kv(5, 20);
    dim3 g_attn(16 * 80);   // (N/64) * B*H

    k_detect<<<dim3(1), blk, 0, stream>>>((const u16*)x, flag);
    k_b2f<<<dim3((BT * D + 255) / 256), blk, 0, stream>>>(x, xres, BT * D, flag);
    // --- self attention ---
    k_layernorm<<<dim3(BT), blk, 0, stream>>>(xres, g1, be1, lnout, D, flag);
    k_gemm<0, false><<<g_gemm, blk, 0, stream>>>(lnout, wq1, q, nullptr, nullptr, BT, D, D, flag);
    k_gemm<0, false><<<g_gemm, blk, 0, stream>>>(lnout, wk1, kbuf, nullptr, nullptr, BT, D, D, flag);
    k_gemm<0, false><<<g_gemm, blk, 0, stream>>>(lnout, wv1, vbuf, nullptr, nullptr, BT, D, D, flag);
    k_attn_flash<<<g_attn, blk, 0, stream>>>(q, kbuf, vbuf, attnout, 1024, 1024, 20);
    k_gemm<2, false><<<g_gemm, blk, 0, stream>>>(attnout, wo1, nullptr, xres, bo1, BT, D, D, flag);
    // --- cross attention ---
    k_layernorm<<<dim3(BT), blk, 0, stream>>>(xres, g2, be2, lnout, D, flag);
    k_gemm<0, false><<<g_gemm, blk, 0, stream>>>(lnout, wq2, q, nullptr, nullptr, BT, D, D, flag);
    k_gemm<0, true><<<g_kv, blk, 0, stream>>>(ctx, wk2, k2, nullptr, nullptr, 308, D, 768, flag);
    k_gemm<0, true><<<g_kv, blk, 0, stream>>>(ctx, wv2, v2, nullptr, nullptr, 308, D, 768, flag);
    k_attn_flash<<<g_attn, blk, 0, stream>>>(q, k2, v2, attnout, 1024, 77, 20);
    k_gemm<2, false><<<g_gemm, blk, 0, stream>>>(attnout, wo2, nullptr, xres, bo2, BT, D, D, flag);
    // --- GEGLU FF ---
    k_layernorm<<<dim3(BT), blk, 0, stream>>>(xres, g3, be3, lnout, D, flag);
    k_gemm_geglu<<<dim3(64, 80), blk, 0, stream>>>(lnout, wff1, bff1, gbuf, BT, 5120, D, 10240, flag);
    k_gemm<3, false><<<g_gemm, blk, 0, stream>>>(gbuf, wff2, d_out, xres, bff2, BT, D, 5120, flag);
}

// Round 5
// 928.745 us; speedup vs baseline: 7.5407x; 3.4173x over previous
//
#include <hip/hip_runtime.h>

typedef unsigned short u16;
typedef __bf16 bf16x8 __attribute__((ext_vector_type(8)));
typedef float f32x4 __attribute__((ext_vector_type(4)));

static __device__ __forceinline__ float bf2f(u16 u) {
    union { unsigned int i; float f; } v; v.i = ((unsigned int)u) << 16; return v.f;
}
static __device__ __forceinline__ u16 f2bf(float f) {
    union { float f; unsigned int i; } v; v.f = f;
    unsigned int b = v.i;
    b += 0x7fffu + ((b >> 16) & 1u);   // RNE
    return (u16)(b >> 16);
}
static __device__ __forceinline__ u16 ldbf(const void* p, size_t i, int isf32) {
    return isf32 ? f2bf(((const float*)p)[i]) : ((const u16*)p)[i];
}
static __device__ __forceinline__ float ldf(const void* p, size_t i, int isf32) {
    return isf32 ? ((const float*)p)[i] : bf2f(((const u16*)p)[i]);
}

// ---------------- dtype detector (insurance; inputs measured fp32) ----------------
__global__ __launch_bounds__(256) void k_detect(const u16* __restrict__ xu, int* __restrict__ flag) {
    u16 v = xu[threadIdx.x * 2];
    int e = (v >> 7) & 0xFF;
    int sane = (e >= 87 && e <= 133) ? 1 : 0;
    int total = __syncthreads_count(sane);
    if (threadIdx.x == 0) flag[0] = (total < 192) ? 1 : 0;
}

// ---------------- x -> f32 residual stream ----------------
__global__ __launch_bounds__(256) void k_b2f(const void* __restrict__ in, float* __restrict__ out, int n,
                                             const int* __restrict__ flagp) {
    int isf32 = *flagp;
    int i = blockIdx.x * 256 + threadIdx.x;
    if (i < n) out[i] = ldf(in, i, isf32);
}

// ---------------- external -> bf16 convert ----------------
__global__ __launch_bounds__(256) void k_cvt(const void* __restrict__ in, u16* __restrict__ out, int n,
                                             const int* __restrict__ flagp) {
    int isf32 = *flagp;
    int i = blockIdx.x * 256 + threadIdx.x;
    if (i < n) out[i] = ldbf(in, i, isf32);
}

// ---------------- weight transpose+convert: W[K,N] (ext) -> Wt[N,K] bf16 ----------------
// K,N multiples of 32 for all weights here.
__global__ __launch_bounds__(256) void k_transpose(const void* __restrict__ W, u16* __restrict__ Wt,
                                                   int K, int N, const int* __restrict__ flagp) {
    int isf32 = *flagp;
    __shared__ u16 T[32][33];
    int k0 = blockIdx.x * 32, n0 = blockIdx.y * 32;
    int tid = threadIdx.x;
    int c = tid & 31, rr = tid >> 5;
    #pragma unroll
    for (int j = 0; j < 4; ++j) {
        int k = rr + j * 8;
        T[k][c] = ldbf(W, (size_t)(k0 + k) * N + n0 + c, isf32);
    }
    __syncthreads();
    #pragma unroll
    for (int j = 0; j < 4; ++j) {
        int n = rr + j * 8;
        Wt[(size_t)(n0 + n) * K + k0 + c] = T[c][n];
    }
}

// ---------------- LayerNorm: fp32 in -> bf16 out ----------------
__global__ __launch_bounds__(256) void k_layernorm(const float* __restrict__ X, const void* __restrict__ G,
                                                   const void* __restrict__ Bb, u16* __restrict__ Y, int D,
                                                   const int* __restrict__ flagp) {
    int isf32 = *flagp;
    int row = blockIdx.x;
    const float* xr = X + (size_t)row * D;
    float s = 0.f, s2 = 0.f;
    for (int i = threadIdx.x; i < D; i += 256) { float v = xr[i]; s += v; s2 += v * v; }
    #pragma unroll
    for (int off = 32; off; off >>= 1) { s += __shfl_down(s, off); s2 += __shfl_down(s2, off); }
    __shared__ float rs[4], rs2[4];
    __shared__ float stat[2];
    int w = threadIdx.x >> 6;
    if ((threadIdx.x & 63) == 0) { rs[w] = s; rs2[w] = s2; }
    __syncthreads();
    if (threadIdx.x == 0) {
        float ts = rs[0] + rs[1] + rs[2] + rs[3];
        float ts2 = rs2[0] + rs2[1] + rs2[2] + rs2[3];
        float mu = ts / D;
        float var = ts2 / D - mu * mu;
        stat[0] = mu; stat[1] = rsqrtf(var + 1e-5f);
    }
    __syncthreads();
    float mu = stat[0], rstd = stat[1];
    u16* yr = Y + (size_t)row * D;
    for (int i = threadIdx.x; i < D; i += 256) {
        yr[i] = f2bf((xr[i] - mu) * rstd * ldf(G, i, isf32) + ldf(Bb, i, isf32));
    }
}

// ============ FAST PATH: 128x128 tile GEMM, A[M,K] bf16 @ Bt[N,K] bf16 ============
// EPI: 0 = bf16 store; 2 = Rf[off] += acc + bias (fp32 in-place; also used for final out)
template <int EPI>
__global__ __launch_bounds__(256) void k_gemm_t(const u16* __restrict__ A, const u16* __restrict__ Bt,
                                                void* __restrict__ Cout, float* __restrict__ Rf,
                                                const void* __restrict__ bias,
                                                int M, int N, int K, const int* __restrict__ flagp) {
    int isf32 = *flagp;
    __shared__ u16 As[128][40];
    __shared__ u16 Bs[128][40];
    int tid = threadIdx.x;
    int row0 = blockIdx.x * 128, col0 = blockIdx.y * 128;
    int wave = tid >> 6, lane = tid & 63;
    int wm = (wave >> 1) * 64, wn = (wave & 1) * 64;
    int quad = lane >> 4, r = lane & 15;
    int srow = tid >> 1, soff = (tid & 1) * 16;
    int garow = row0 + srow;
    const u16* Ap = A + (size_t)garow * K + soff;
    const u16* Bp = Bt + (size_t)(col0 + srow) * K + soff;
    f32x4 acc[4][4] = {};
    for (int k0 = 0; k0 < K; k0 += 32) {
        uint4 a0 = {0u,0u,0u,0u}, a1 = {0u,0u,0u,0u};
        if (garow < M) {
            a0 = *(const uint4*)(Ap + k0);
            a1 = *(const uint4*)(Ap + k0 + 8);
        }
        uint4 b0 = *(const uint4*)(Bp + k0);
        uint4 b1 = *(const uint4*)(Bp + k0 + 8);
        __syncthreads();
        *(uint4*)&As[srow][soff] = a0;
        *(uint4*)&As[srow][soff + 8] = a1;
        *(uint4*)&Bs[srow][soff] = b0;
        *(uint4*)&Bs[srow][soff + 8] = b1;
        __syncthreads();
        bf16x8 af[4], bfv[4];
        #pragma unroll
        for (int i = 0; i < 4; ++i) af[i] = *(const bf16x8*)&As[wm + i * 16 + r][quad * 8];
        #pragma unroll
        for (int g = 0; g < 4; ++g) bfv[g] = *(const bf16x8*)&Bs[wn + g * 16 + r][quad * 8];
        #pragma unroll
        for (int i = 0; i < 4; ++i)
            #pragma unroll
            for (int g = 0; g < 4; ++g)
                acc[i][g] = __builtin_amdgcn_mfma_f32_16x16x32_bf16(af[i], bfv[g], acc[i][g], 0, 0, 0);
    }
    #pragma unroll
    for (int i = 0; i < 4; ++i) {
        int grow = row0 + wm + i * 16 + quad * 4;    // M%4==0 for all uses
        if (grow >= M) continue;
        #pragma unroll
        for (int g = 0; g < 4; ++g) {
            int gcol = col0 + wn + g * 16 + r;
            float bv = (EPI == 2) ? ldf(bias, gcol, isf32) : 0.f;
            #pragma unroll
            for (int t = 0; t < 4; ++t) {
                float v = acc[i][g][t];
                size_t off = (size_t)(grow + t) * N + gcol;
                if (EPI == 0) ((u16*)Cout)[off] = f2bf(v);
                else Rf[off] += v + bv;
            }
        }
    }
}

// ============ FAST PATH: GEGLU ff1, 128 rows x 64 cols per half, Nout=5120 ============
__global__ __launch_bounds__(256) void k_geglu_t(const u16* __restrict__ A, const u16* __restrict__ Bt,
                                                 const void* __restrict__ bias, u16* __restrict__ Out,
                                                 int M, int K, const int* __restrict__ flagp) {
    const int Nout = 5120;
    int isf32 = *flagp;
    __shared__ u16 As[128][40];
    __shared__ u16 Bs[2][64][40];
    int tid = threadIdx.x;
    int row0 = blockIdx.x * 128, col0 = blockIdx.y * 64;
    int wave = tid >> 6, lane = tid & 63;
    int quad = lane >> 4, r = lane & 15;
    int srow = tid >> 1, soff = (tid & 1) * 16;
    const u16* Ap = A + (size_t)(row0 + srow) * K + soff;
    int bh = tid >> 7, bn = (tid >> 1) & 63;
    const u16* Bp = Bt + (size_t)(bh * Nout + col0 + bn) * K + soff;
    f32x4 acc[2][2][4] = {};
    for (int k0 = 0; k0 < K; k0 += 32) {
        uint4 a0 = *(const uint4*)(Ap + k0);
        uint4 a1 = *(const uint4*)(Ap + k0 + 8);
        uint4 b0 = *(const uint4*)(Bp + k0);
        uint4 b1 = *(const uint4*)(Bp + k0 + 8);
        __syncthreads();
        *(uint4*)&As[srow][soff] = a0;
        *(uint4*)&As[srow][soff + 8] = a1;
        *(uint4*)&Bs[bh][bn][soff] = b0;
        *(uint4*)&Bs[bh][bn][soff + 8] = b1;
        __syncthreads();
        bf16x8 af[2], bv[2][4];
        #pragma unroll
        for (int i = 0; i < 2; ++i) af[i] = *(const bf16x8*)&As[wave * 32 + i * 16 + r][quad * 8];
        #pragma unroll
        for (int p = 0; p < 2; ++p)
            #pragma unroll
            for (int g = 0; g < 4; ++g) bv[p][g] = *(const bf16x8*)&Bs[p][g * 16 + r][quad * 8];
        #pragma unroll
        for (int p = 0; p < 2; ++p)
            #pragma unroll
            for (int i = 0; i < 2; ++i)
                #pragma unroll
                for (int g = 0; g < 4; ++g)
                    acc[p][i][g] = __builtin_amdgcn_mfma_f32_16x16x32_bf16(af[i], bv[p][g], acc[p][i][g], 0, 0, 0);
    }
    #pragma unroll
    for (int i = 0; i < 2; ++i) {
        int grow = row0 + wave * 32 + i * 16 + quad * 4;
        #pragma unroll
        for (int g = 0; g < 4; ++g) {
            int gcol = col0 + g * 16 + r;
            float bva = ldf(bias, gcol, isf32);
            float bvu = ldf(bias, Nout + gcol, isf32);
            #pragma unroll
            for (int t = 0; t < 4; ++t) {
                float a = acc[0][i][g][t] + bva;
                float u = acc[1][i][g][t] + bvu;
                float th = tanhf(0.7978845608f * (u + 0.044715f * u * u * u));
                float gl = 0.5f * u * (1.f + th);
                Out[(size_t)(grow + t) * Nout + gcol] = f2bf(a * gl);
            }
        }
    }
}

// ============ FALLBACK: round-4 64x64 GEMM (known-good) ============
template <int EPI, bool AEXT>
__global__ __launch_bounds__(256) void k_gemm(const void* __restrict__ A, const void* __restrict__ B,
                                              void* __restrict__ Cout, float* __restrict__ Rf,
                                              const void* __restrict__ bias,
                                              int M, int N, int K, const int* __restrict__ flagp) {
    int isf32 = *flagp;
    __shared__ u16 As[64][40];
    __shared__ u16 Bs[64][40];
    int tid = threadIdx.x;
    int row0 = blockIdx.x * 64, col0 = blockIdx.y * 64;
    int wave = tid >> 6, lane = tid & 63;
    int wm = (wave >> 1) * 32, wn = (wave & 1) * 32;
    int quad = lane >> 4, r = lane & 15;
    int arow = tid >> 2, akk = (tid & 3) * 8;
    int bnl = tid & 63, bkk = (tid >> 6) * 8;
    int garow = row0 + arow;
    f32x4 acc[2][2] = {};
    for (int k0 = 0; k0 < K; k0 += 32) {
        uint4 aval = {0u, 0u, 0u, 0u};
        if (garow < M) {
            if (AEXT && isf32) {
                const float* Af = (const float*)A;
                u16 t[8];
                #pragma unroll
                for (int j = 0; j < 8; ++j) t[j] = f2bf(Af[(size_t)garow * K + k0 + akk + j]);
                aval = *(uint4*)t;
            } else {
                aval = *(const uint4*)((const u16*)A + (size_t)garow * K + k0 + akk);
            }
        }
        u16 btmp[8];
        #pragma unroll
        for (int j = 0; j < 8; ++j) btmp[j] = ldbf(B, (size_t)(k0 + bkk + j) * N + col0 + bnl, isf32);
        __syncthreads();
        *(uint4*)(&As[arow][akk]) = aval;
        *(uint4*)(&Bs[bnl][bkk]) = *(uint4*)btmp;
        __syncthreads();
        bf16x8 a0 = *(const bf16x8*)(&As[wm + r][quad * 8]);
        bf16x8 a1 = *(const bf16x8*)(&As[wm + 16 + r][quad * 8]);
        bf16x8 b0 = *(const bf16x8*)(&Bs[wn + r][quad * 8]);
        bf16x8 b1 = *(const bf16x8*)(&Bs[wn + 16 + r][quad * 8]);
        acc[0][0] = __builtin_amdgcn_mfma_f32_16x16x32_bf16(a0, b0, acc[0][0], 0, 0, 0);
        acc[0][1] = __builtin_amdgcn_mfma_f32_16x16x32_bf16(a0, b1, acc[0][1], 0, 0, 0);
        acc[1][0] = __builtin_amdgcn_mfma_f32_16x16x32_bf16(a1, b0, acc[1][0], 0, 0, 0);
        acc[1][1] = __builtin_amdgcn_mfma_f32_16x16x32_bf16(a1, b1, acc[1][1], 0, 0, 0);
    }
    #pragma unroll
    for (int i = 0; i < 2; ++i)
        #pragma unroll
        for (int jn = 0; jn < 2; ++jn)
            #pragma unroll
            for (int t = 0; t < 4; ++t) {
                int grow = row0 + wm + i * 16 + quad * 4 + t;
                int gcol = col0 + wn + jn * 16 + r;
                if (grow >= M) continue;
                float v = acc[i][jn][t];
                size_t off = (size_t)grow * N + gcol;
                if (EPI == 0) {
                    ((u16*)Cout)[off] = f2bf(v);
                } else if (EPI == 2) {
                    Rf[off] += v + ldf(bias, gcol, isf32);
                } else {
                    ((float*)Cout)[off] = v + ldf(bias, gcol, isf32) + Rf[off];
                }
            }
}

// ============ FALLBACK: round-4 geglu ============
__global__ __launch_bounds__(256) void k_gemm_geglu(const u16* __restrict__ A, const void* __restrict__ B,
                                                    const void* __restrict__ bias, u16* __restrict__ Out,
                                                    int M, int Nout, int K, int ldb,
                                                    const int* __restrict__ flagp) {
    int isf32 = *flagp;
    __shared__ u16 As[64][40];
    __shared__ u16 Bs[64][40];
    int tid = threadIdx.x;
    int row0 = blockIdx.x * 64, col0 = blockIdx.y * 64;
    int wave = tid >> 6, lane = tid & 63;
    int wm = (wave >> 1) * 32, wn = (wave & 1) * 32;
    int quad = lane >> 4, r = lane & 15;
    int arow = tid >> 2, akk = (tid & 3) * 8;
    int bnl = tid & 63, bkk = (tid >> 6) * 8;
    int garow = row0 + arow;
    f32x4 acc[2][2][2] = {};
    for (int p = 0; p < 2; ++p) {
        for (int k0 = 0; k0 < K; k0 += 32) {
            uint4 aval = {0u, 0u, 0u, 0u};
            if (garow < M) aval = *(const uint4*)(A + (size_t)garow * K + k0 + akk);
            u16 btmp[8];
            #pragma unroll
            for (int j = 0; j < 8; ++j)
                btmp[j] = ldbf(B, (size_t)(k0 + bkk + j) * ldb + p * Nout + col0 + bnl, isf32);
            __syncthreads();
            *(uint4*)(&As[arow][akk]) = aval;
            *(uint4*)(&Bs[bnl][bkk]) = *(uint4*)btmp;
            __syncthreads();
            bf16x8 a0 = *(const bf16x8*)(&As[wm + r][quad * 8]);
            bf16x8 a1 = *(const bf16x8*)(&As[wm + 16 + r][quad * 8]);
            bf16x8 b0 = *(const bf16x8*)(&Bs[wn + r][quad * 8]);
            bf16x8 b1 = *(const bf16x8*)(&Bs[wn + 16 + r][quad * 8]);
            acc[p][0][0] = __builtin_amdgcn_mfma_f32_16x16x32_bf16(a0, b0, acc[p][0][0], 0, 0, 0);
            acc[p][0][1] = __builtin_amdgcn_mfma_f32_16x16x32_bf16(a0, b1, acc[p][0][1], 0, 0, 0);
            acc[p][1][0] = __builtin_amdgcn_mfma_f32_16x16x32_bf16(a1, b0, acc[p][1][0], 0, 0, 0);
            acc[p][1][1] = __builtin_amdgcn_mfma_f32_16x16x32_bf16(a1, b1, acc[p][1][1], 0, 0, 0);
        }
    }
    #pragma unroll
    for (int i = 0; i < 2; ++i)
        #pragma unroll
        for (int jn = 0; jn < 2; ++jn)
            #pragma unroll
            for (int t = 0; t < 4; ++t) {
                int grow = row0 + wm + i * 16 + quad * 4 + t;
                int gcol = col0 + wn + jn * 16 + r;
                if (grow >= M) continue;
                float a = acc[0][i][jn][t] + ldf(bias, gcol, isf32);
                float u = acc[1][i][jn][t] + ldf(bias, Nout + gcol, isf32);
                float th = tanhf(0.7978845608f * (u + 0.044715f * u * u * u));
                float gl = 0.5f * u * (1.f + th);
                Out[(size_t)grow * Nout + gcol] = f2bf(a * gl);
            }
}

// ---------------- MFMA flash attention (parameterized strides) ----------------
__global__ __launch_bounds__(256) void k_attn_flash(const u16* __restrict__ Q, const u16* __restrict__ K,
                                                    const u16* __restrict__ V, u16* __restrict__ O,
                                                    int N, int Mkv, int H, int ldq, int ldkv, int ldo) {
    __shared__ u16 Sp[4][16][40];
    __shared__ u16 VT[64][40];
    int nt = N / 64;
    int qt = blockIdx.x % nt;
    int bh = blockIdx.x / nt;
    int h = bh % H, b = bh / H;
    int tid = threadIdx.x, wave = tid >> 6, lane = tid & 63;
    int quad = lane >> 4, r = lane & 15;
    int q0 = qt * 64 + wave * 16;

    const u16* qbase = Q + ((size_t)(b * N + q0 + r)) * ldq + h * 64;
    bf16x8 aq0 = *(const bf16x8*)(qbase + quad * 8);
    bf16x8 aq1 = *(const bf16x8*)(qbase + 32 + quad * 8);

    f32x4 accO[4] = {};
    float m_i[4] = {-1e30f, -1e30f, -1e30f, -1e30f};
    float l_i[4] = {0.f, 0.f, 0.f, 0.f};

    int vkv = tid & 31, vdg = tid >> 5;

    for (int kv0 = 0; kv0 < Mkv; kv0 += 32) {
        int kr0 = min(kv0 + r, Mkv - 1);
        int kr1 = min(kv0 + 16 + r, Mkv - 1);
        const u16* kb0 = K + ((size_t)(b * Mkv + kr0)) * ldkv + h * 64;
        const u16* kb1 = K + ((size_t)(b * Mkv + kr1)) * ldkv + h * 64;
        bf16x8 bk00 = *(const bf16x8*)(kb0 + quad * 8);
        bf16x8 bk01 = *(const bf16x8*)(kb0 + 32 + quad * 8);
        bf16x8 bk10 = *(const bf16x8*)(kb1 + quad * 8);
        bf16x8 bk11 = *(const bf16x8*)(kb1 + 32 + quad * 8);
        int vrow = min(kv0 + vkv, Mkv - 1);
        uint4 vv = *(const uint4*)(V + ((size_t)(b * Mkv + vrow)) * ldkv + h * 64 + vdg * 8);

        __syncthreads();
        VT[vdg * 8 + 0][vkv] = (u16)(vv.x);
        VT[vdg * 8 + 1][vkv] = (u16)(vv.x >> 16);
        VT[vdg * 8 + 2][vkv] = (u16)(vv.y);
        VT[vdg * 8 + 3][vkv] = (u16)(vv.y >> 16);
        VT[vdg * 8 + 4][vkv] = (u16)(vv.z);
        VT[vdg * 8 + 5][vkv] = (u16)(vv.z >> 16);
        VT[vdg * 8 + 6][vkv] = (u16)(vv.w);
        VT[vdg * 8 + 7][vkv] = (u16)(vv.w >> 16);
        __syncthreads();

        f32x4 s0 = {}, s1 = {};
        s0 = __builtin_amdgcn_mfma_f32_16x16x32_bf16(aq0, bk00, s0, 0, 0, 0);
        s0 = __builtin_amdgcn_mfma_f32_16x16x32_bf16(aq1, bk01, s0, 0, 0, 0);
        s1 = __builtin_amdgcn_mfma_f32_16x16x32_bf16(aq0, bk10, s1, 0, 0, 0);
        s1 = __builtin_amdgcn_mfma_f32_16x16x32_bf16(aq1, bk11, s1, 0, 0, 0);
        bool mask0 = (kv0 + r) >= Mkv;
        bool mask1 = (kv0 + 16 + r) >= Mkv;

        #pragma unroll
        for (int t = 0; t < 4; ++t) {
            float a = mask0 ? -1e30f : s0[t] * 0.125f;
            float c = mask1 ? -1e30f : s1[t] * 0.125f;
            float mx = fmaxf(a, c);
            mx = fmaxf(mx, __shfl_xor(mx, 1));
            mx = fmaxf(mx, __shfl_xor(mx, 2));
            mx = fmaxf(mx, __shfl_xor(mx, 4));
            mx = fmaxf(mx, __shfl_xor(mx, 8));
            float mn = fmaxf(m_i[t], mx);
            float alpha = __expf(m_i[t] - mn);
            float p0 = __expf(a - mn);
            float p1 = __expf(c - mn);
            float ps = p0 + p1;
            ps += __shfl_xor(ps, 1);
            ps += __shfl_xor(ps, 2);
            ps += __shfl_xor(ps, 4);
            ps += __shfl_xor(ps, 8);
            l_i[t] = l_i[t] * alpha + ps;
            m_i[t] = mn;
            accO[0][t] *= alpha; accO[1][t] *= alpha; accO[2][t] *= alpha; accO[3][t] *= alpha;
            Sp[wave][quad * 4 + t][r] = f2bf(p0);
            Sp[wave][quad * 4 + t][16 + r] = f2bf(p1);
        }

        bf16x8 ap = *(const bf16x8*)(&Sp[wave][r][quad * 8]);
        #pragma unroll
        for (int g = 0; g < 4; ++g) {
            bf16x8 bvv = *(const bf16x8*)(&VT[g * 16 + r][quad * 8]);
            accO[g] = __builtin_amdgcn_mfma_f32_16x16x32_bf16(ap, bvv, accO[g], 0, 0, 0);
        }
    }

    u16* ob = O + ((size_t)(b * N + q0)) * ldo + h * 64;
    #pragma unroll
    for (int t = 0; t < 4; ++t) {
        float inv = 1.f / l_i[t];
        #pragma unroll
        for (int g = 0; g < 4; ++g)
            ob[(size_t)(quad * 4 + t) * ldo + g * 16 + r] = f2bf(accO[g][t] * inv);
    }
}

extern "C" void kernel_launch(void* const* d_in, const int* in_sizes, int n_in,
                              void* d_out, int out_size, void* d_ws, size_t ws_size,
                              hipStream_t stream) {
    const void* x    = d_in[0];
    const void* ctx  = d_in[1];
    const void* g1   = d_in[2];
    const void* be1  = d_in[3];
    const void* wq1  = d_in[4];
    const void* wk1  = d_in[5];
    const void* wv1  = d_in[6];
    const void* wo1  = d_in[7];
    const void* bo1  = d_in[8];
    const void* g2   = d_in[9];
    const void* be2  = d_in[10];
    const void* wq2  = d_in[11];
    const void* wk2  = d_in[12];
    const void* wv2  = d_in[13];
    const void* wo2  = d_in[14];
    const void* bo2  = d_in[15];
    const void* g3   = d_in[16];
    const void* be3  = d_in[17];
    const void* wff1 = d_in[18];
    const void* bff1 = d_in[19];
    const void* wff2 = d_in[20];
    const void* bff2 = d_in[21];

    const int BT = 4096, D = 1280;
    dim3 blk(256);
    char* ws = (char*)d_ws;

    const size_t NEED_FAST = 117393664;
    if (ws_size >= NEED_FAST) {
        // ---------- fast path ----------
        int*   flag   = (int*)(ws);
        u16* lnout    = (u16*)(ws + 256);            // 4096x1280 bf16
        u16* qkv      = (u16*)(ws + 10486016);       // 4096x3840 bf16 (region R)
        u16* attnout  = (u16*)(ws + 10486016 + 31457280);
        u16* gbuf     = (u16*)(ws + 10486016);       // 4096x5120 bf16, aliases qkv+attnout
        u16* ctxb     = (u16*)(ws + 52429056);       // 308x768 bf16
        u16* kv2      = (u16*)(ws + 52902144);       // 308x2560 bf16
        u16* wqkv1t   = (u16*)(ws + 54479104);       // [3840][1280]
        u16* wo1t     = (u16*)(ws + 64309504);       // [1280][1280]
        u16* wq2t     = (u16*)(ws + 67586304);
        u16* wkv2t    = (u16*)(ws + 70863104);       // [2560][768]
        u16* wo2t     = (u16*)(ws + 74795264);
        u16* wff1t    = (u16*)(ws + 78072064);       // [10240][1280]
        u16* wff2t    = (u16*)(ws + 104286464);      // [1280][5120]
        float* xres   = (float*)d_out;               // residual lives in the fp32 output

        k_detect<<<dim3(1), blk, 0, stream>>>((const u16*)x, flag);
        k_b2f<<<dim3((BT * D + 255) / 256), blk, 0, stream>>>(x, xres, BT * D, flag);
        // weight transposes (once per launch)
        k_transpose<<<dim3(40, 40), blk, 0, stream>>>(wq1, wqkv1t, 1280, 1280, flag);
        k_transpose<<<dim3(40, 40), blk, 0, stream>>>(wk1, wqkv1t + 1280 * 1280, 1280, 1280, flag);
        k_transpose<<<dim3(40, 40), blk, 0, stream>>>(wv1, wqkv1t + 2 * 1280 * 1280, 1280, 1280, flag);
        k_transpose<<<dim3(40, 40), blk, 0, stream>>>(wo1, wo1t, 1280, 1280, flag);
        k_transpose<<<dim3(40, 40), blk, 0, stream>>>(wq2, wq2t, 1280, 1280, flag);
        k_transpose<<<dim3(24, 40), blk, 0, stream>>>(wk2, wkv2t, 768, 1280, flag);
        k_transpose<<<dim3(24, 40), blk, 0, stream>>>(wv2, wkv2t + 1280 * 768, 768, 1280, flag);
        k_transpose<<<dim3(40, 40), blk, 0, stream>>>(wo2, wo2t, 1280, 1280, flag);
        k_transpose<<<dim3(40, 320), blk, 0, stream>>>(wff1, wff1t, 1280, 10240, flag);
        k_transpose<<<dim3(160, 40), blk, 0, stream>>>(wff2, wff2t, 5120, 1280, flag);
        k_cvt<<<dim3((308 * 768 + 255) / 256), blk, 0, stream>>>(ctx, ctxb, 308 * 768, flag);
        // --- self attention ---
        k_layernorm<<<dim3(BT), blk, 0, stream>>>(xres, g1, be1, lnout, D, flag);
        k_gemm_t<0><<<dim3(32, 30), blk, 0, stream>>>(lnout, wqkv1t, qkv, nullptr, nullptr, BT, 3840, D, flag);
        k_attn_flash<<<dim3(16 * 80), blk, 0, stream>>>(qkv, qkv + 1280, qkv + 2560, attnout,
                                                        1024, 1024, 20, 3840, 3840, 1280);
        k_gemm_t<2><<<dim3(32, 10), blk, 0, stream>>>(attnout, wo1t, nullptr, xres, bo1, BT, D, D, flag);
        // --- cross attention ---
        k_layernorm<<<dim3(BT), blk, 0, stream>>>(xres, g2, be2, lnout, D, flag);
        k_gemm_t<0><<<dim3(32, 10), blk, 0, stream>>>(lnout, wq2t, qkv, nullptr, nullptr, BT, D, D, flag);
        k_gemm_t<0><<<dim3(3, 20), blk, 0, stream>>>(ctxb, wkv2t, kv2, nullptr, nullptr, 308, 2560, 768, flag);
        k_attn_flash<<<dim3(16 * 80), blk, 0, stream>>>(qkv, kv2, kv2 + 1280, attnout,
                                                        1024, 77, 20, 1280, 2560, 1280);
        k_gemm_t<2><<<dim3(32, 10), blk, 0, stream>>>(attnout, wo2t, nullptr, xres, bo2, BT, D, D, flag);
        // --- GEGLU FF ---
        k_layernorm<<<dim3(BT), blk, 0, stream>>>(xres, g3, be3, lnout, D, flag);
        k_geglu_t<<<dim3(32, 80), blk, 0, stream>>>(lnout, wff1t, bff1, gbuf, BT, D, flag);
        k_gemm_t<2><<<dim3(32, 10), blk, 0, stream>>>(gbuf, wff2t, nullptr, xres, bff2, BT, D, 5120, flag);
    } else {
        // ---------- fallback: round-4 path (known-good, ~75 MB ws) ----------
        int*   flag    = (int*)(ws);
        float* xres    = (float*)(ws + 256);
        u16* lnout     = (u16*)(ws + 20971776);
        u16* q         = (u16*)(ws + 31457536);
        u16* kbuf      = (u16*)(ws + 41943296);
        u16* vbuf      = (u16*)(ws + 52429056);
        u16* attnout   = (u16*)(ws + 62914816);
        u16* k2        = (u16*)(ws + 73400576);
        u16* v2        = (u16*)(ws + 74189056);
        u16* gbuf      = (u16*)(ws + 31457536);

        dim3 g_gemm(64, 20);
        dim3 g_kv(5, 20);
        dim3 g_attn(16 * 80);

        k_detect<<<dim3(1), blk, 0, stream>>>((const u16*)x, flag);
        k_b2f<<<dim3((BT * D + 255) / 256), blk, 0, stream>>>(x, xres, BT * D, flag);
        k_layernorm<<<dim3(BT), blk, 0, stream>>>(xres, g1, be1, lnout, D, flag);
        k_gemm<0, false><<<g_gemm, blk, 0, stream>>>(lnout, wq1, q, nullptr, nullptr, BT, D, D, flag);
        k_gemm<0, false><<<g_gemm, blk, 0, stream>>>(lnout, wk1, kbuf, nullptr, nullptr, BT, D, D, flag);
        k_gemm<0, false><<<g_gemm, blk, 0, stream>>>(lnout, wv1, vbuf, nullptr, nullptr, BT, D, D, flag);
        k_attn_flash<<<g_attn, blk, 0, stream>>>(q, kbuf, vbuf, attnout, 1024, 1024, 20, 1280, 1280, 1280);
        k_gemm<2, false><<<g_gemm, blk, 0, stream>>>(attnout, wo1, nullptr, xres, bo1, BT, D, D, flag);
        k_layernorm<<<dim3(BT), blk, 0, stream>>>(xres, g2, be2, lnout, D, flag);
        k_gemm<0, false><<<g_gemm, blk, 0, stream>>>(lnout, wq2, q, nullptr, nullptr, BT, D, D, flag);
        k_gemm<0, true><<<g_kv, blk, 0, stream>>>(ctx, wk2, k2, nullptr, nullptr, 308, D, 768, flag);
        k_gemm<0, true><<<g_kv, blk, 0, stream>>>(ctx, wv2, v2, nullptr, nullptr, 308, D, 768, flag);
        k_attn_flash<<<g_attn, blk, 0, stream>>>(q, k2, v2, attnout, 1024, 77, 20, 1280, 1280, 1280);
        k_gemm<2, false><<<g_gemm, blk, 0, stream>>>(attnout, wo2, nullptr, xres, bo2, BT, D, D, flag);
        k_layernorm<<<dim3(BT), blk, 0, stream>>>(xres, g3, be3, lnout, D, flag);
        k_gemm_geglu<<<dim3(64, 80), blk, 0, stream>>>(lnout, wff1, bff1, gbuf, BT, 5120, D, 10240, flag);
        k_gemm<3, false><<<g_gemm, blk, 0, stream>>>(gbuf, wff2, d_out, xres, bff2, BT, D, 5120, flag);
    }
}

// Round 6
// 905.865 us; speedup vs baseline: 7.7312x; 1.0253x over previous
//
#include <hip/hip_runtime.h>

typedef unsigned short u16;
typedef __bf16 bf16x8 __attribute__((ext_vector_type(8)));
typedef float f32x4 __attribute__((ext_vector_type(4)));

static __device__ __forceinline__ float bf2f(u16 u) {
    union { unsigned int i; float f; } v; v.i = ((unsigned int)u) << 16; return v.f;
}
static __device__ __forceinline__ u16 f2bf(float f) {
    union { float f; unsigned int i; } v; v.f = f;
    unsigned int b = v.i;
    b += 0x7fffu + ((b >> 16) & 1u);   // RNE
    return (u16)(b >> 16);
}
static __device__ __forceinline__ u16 ldbf(const void* p, size_t i, int isf32) {
    return isf32 ? f2bf(((const float*)p)[i]) : ((const u16*)p)[i];
}
static __device__ __forceinline__ float ldf(const void* p, size_t i, int isf32) {
    return isf32 ? ((const float*)p)[i] : bf2f(((const u16*)p)[i]);
}
// async global->LDS, 16B per lane; lds dest = wave-uniform base + lane*16 (m97/m104)
static __device__ __forceinline__ void glds16(const u16* g, u16* l) {
    __builtin_amdgcn_global_load_lds(
        (const __attribute__((address_space(1))) unsigned int*)g,
        (__attribute__((address_space(3))) unsigned int*)l,
        16, 0, 0);
}

// ---------------- dtype detector (insurance; inputs measured fp32) ----------------
__global__ __launch_bounds__(256) void k_detect(const u16* __restrict__ xu, int* __restrict__ flag) {
    u16 v = xu[threadIdx.x * 2];
    int e = (v >> 7) & 0xFF;
    int sane = (e >= 87 && e <= 133) ? 1 : 0;
    int total = __syncthreads_count(sane);
    if (threadIdx.x == 0) flag[0] = (total < 192) ? 1 : 0;
}

// ---------------- x -> f32 residual stream ----------------
__global__ __launch_bounds__(256) void k_b2f(const void* __restrict__ in, float* __restrict__ out, int n,
                                             const int* __restrict__ flagp) {
    int isf32 = *flagp;
    int i = blockIdx.x * 256 + threadIdx.x;
    if (i < n) out[i] = ldf(in, i, isf32);
}

// ---------------- external -> bf16 convert ----------------
__global__ __launch_bounds__(256) void k_cvt(const void* __restrict__ in, u16* __restrict__ out, int n,
                                             const int* __restrict__ flagp) {
    int isf32 = *flagp;
    int i = blockIdx.x * 256 + threadIdx.x;
    if (i < n) out[i] = ldbf(in, i, isf32);
}

// ---------------- weight transpose+convert: W[K,N] (ext) -> Wt[N,K] bf16 ----------------
__global__ __launch_bounds__(256) void k_transpose(const void* __restrict__ W, u16* __restrict__ Wt,
                                                   int K, int N, const int* __restrict__ flagp) {
    int isf32 = *flagp;
    __shared__ u16 T[32][33];
    int k0 = blockIdx.x * 32, n0 = blockIdx.y * 32;
    int tid = threadIdx.x;
    int c = tid & 31, rr = tid >> 5;
    #pragma unroll
    for (int j = 0; j < 4; ++j) {
        int k = rr + j * 8;
        T[k][c] = ldbf(W, (size_t)(k0 + k) * N + n0 + c, isf32);
    }
    __syncthreads();
    #pragma unroll
    for (int j = 0; j < 4; ++j) {
        int n = rr + j * 8;
        Wt[(size_t)(n0 + n) * K + k0 + c] = T[c][n];
    }
}

// ---------------- LayerNorm: fp32 in -> bf16 out ----------------
__global__ __launch_bounds__(256) void k_layernorm(const float* __restrict__ X, const void* __restrict__ G,
                                                   const void* __restrict__ Bb, u16* __restrict__ Y, int D,
                                                   const int* __restrict__ flagp) {
    int isf32 = *flagp;
    int row = blockIdx.x;
    const float* xr = X + (size_t)row * D;
    float s = 0.f, s2 = 0.f;
    for (int i = threadIdx.x; i < D; i += 256) { float v = xr[i]; s += v; s2 += v * v; }
    #pragma unroll
    for (int off = 32; off; off >>= 1) { s += __shfl_down(s, off); s2 += __shfl_down(s2, off); }
    __shared__ float rs[4], rs2[4];
    __shared__ float stat[2];
    int w = threadIdx.x >> 6;
    if ((threadIdx.x & 63) == 0) { rs[w] = s; rs2[w] = s2; }
    __syncthreads();
    if (threadIdx.x == 0) {
        float ts = rs[0] + rs[1] + rs[2] + rs[3];
        float ts2 = rs2[0] + rs2[1] + rs2[2] + rs2[3];
        float mu = ts / D;
        float var = ts2 / D - mu * mu;
        stat[0] = mu; stat[1] = rsqrtf(var + 1e-5f);
    }
    __syncthreads();
    float mu = stat[0], rstd = stat[1];
    u16* yr = Y + (size_t)row * D;
    for (int i = threadIdx.x; i < D; i += 256) {
        yr[i] = f2bf((xr[i] - mu) * rstd * ldf(G, i, isf32) + ldf(Bb, i, isf32));
    }
}

// ============ FAST PATH: 128x128 tile GEMM via global_load_lds, xor-swizzled LDS ============
// As/Bs: 128 rows x 32 k, unpadded; 16B chunk for (row,q) stored at chunk index
// row*4 + (q ^ ((row>>1)&3))  -> b128 frag reads are 2-way (free, m136).
// EPI: 0 = bf16 store; 2 = Rf[off] += acc + bias (fp32 in-place; also final out)
template <int EPI>
__global__ __launch_bounds__(256) void k_gemm_t(const u16* __restrict__ A, const u16* __restrict__ Bt,
                                                void* __restrict__ Cout, float* __restrict__ Rf,
                                                const void* __restrict__ bias,
                                                int M, int N, int K, const int* __restrict__ flagp) {
    int isf32 = *flagp;
    __shared__ __align__(16) u16 As[4096];
    __shared__ __align__(16) u16 Bs[4096];
    int tid = threadIdx.x;
    int row0 = blockIdx.x * 128, col0 = blockIdx.y * 128;
    int wave = tid >> 6, lane = tid & 63;
    int wm = (wave >> 1) * 64, wn = (wave & 1) * 64;
    int quad = lane >> 4, r = lane & 15;
    // staging: chunk ids c0 in [0,256), c1 in [256,512)
    int c0 = wave * 64 + lane, c1 = 256 + c0;
    int ar0 = c0 >> 2, aq0 = (c0 & 3) ^ ((ar0 >> 1) & 3);
    int ar1 = c1 >> 2, aq1 = (c1 & 3) ^ ((ar1 >> 1) & 3);
    const u16* Ag0 = A + (size_t)min(row0 + ar0, M - 1) * K + aq0 * 8;
    const u16* Ag1 = A + (size_t)min(row0 + ar1, M - 1) * K + aq1 * 8;
    const u16* Bg0 = Bt + (size_t)(col0 + ar0) * K + aq0 * 8;
    const u16* Bg1 = Bt + (size_t)(col0 + ar1) * K + aq1 * 8;
    u16* lA0 = As + wave * 512;
    u16* lA1 = As + 2048 + wave * 512;
    u16* lB0 = Bs + wave * 512;
    u16* lB1 = Bs + 2048 + wave * 512;
    f32x4 acc[4][4] = {};
    for (int k0 = 0; k0 < K; k0 += 32) {
        __syncthreads();          // previous frag reads complete
        glds16(Ag0 + k0, lA0);
        glds16(Ag1 + k0, lA1);
        glds16(Bg0 + k0, lB0);
        glds16(Bg1 + k0, lB1);
        __syncthreads();          // DMA drained (vmcnt(0) before barrier)
        bf16x8 af[4], bfv[4];
        #pragma unroll
        for (int i = 0; i < 4; ++i) {
            int row = wm + i * 16 + r;
            af[i] = *(const bf16x8*)(As + (row * 4 + (quad ^ ((row >> 1) & 3))) * 8);
        }
        #pragma unroll
        for (int g = 0; g < 4; ++g) {
            int row = wn + g * 16 + r;
            bfv[g] = *(const bf16x8*)(Bs + (row * 4 + (quad ^ ((row >> 1) & 3))) * 8);
        }
        #pragma unroll
        for (int i = 0; i < 4; ++i)
            #pragma unroll
            for (int g = 0; g < 4; ++g)
                acc[i][g] = __builtin_amdgcn_mfma_f32_16x16x32_bf16(af[i], bfv[g], acc[i][g], 0, 0, 0);
    }
    #pragma unroll
    for (int i = 0; i < 4; ++i) {
        int grow = row0 + wm + i * 16 + quad * 4;    // M%4==0 for all uses
        if (grow >= M) continue;
        #pragma unroll
        for (int g = 0; g < 4; ++g) {
            int gcol = col0 + wn + g * 16 + r;
            float bv = (EPI == 2) ? ldf(bias, gcol, isf32) : 0.f;
            #pragma unroll
            for (int t = 0; t < 4; ++t) {
                float v = acc[i][g][t];
                size_t off = (size_t)(grow + t) * N + gcol;
                if (EPI == 0) ((u16*)Cout)[off] = f2bf(v);
                else Rf[off] += v + bv;
            }
        }
    }
}

// ============ FAST PATH: GEGLU ff1 via global_load_lds; Nout=5120 ============
// Bs rows: [p*64 + n] for halves p=0,1; sigmoid-form gelu epilogue.
__global__ __launch_bounds__(256) void k_geglu_t(const u16* __restrict__ A, const u16* __restrict__ Bt,
                                                 const void* __restrict__ bias, u16* __restrict__ Out,
                                                 int M, int K, const int* __restrict__ flagp) {
    const int Nout = 5120;
    int isf32 = *flagp;
    __shared__ __align__(16) u16 As[4096];
    __shared__ __align__(16) u16 Bs[4096];
    int tid = threadIdx.x;
    int row0 = blockIdx.x * 128, col0 = blockIdx.y * 64;
    int wave = tid >> 6, lane = tid & 63;
    int quad = lane >> 4, r = lane & 15;
    int c0 = wave * 64 + lane, c1 = 256 + c0;
    int ar0 = c0 >> 2, aq0 = (c0 & 3) ^ ((ar0 >> 1) & 3);
    int ar1 = c1 >> 2, aq1 = (c1 & 3) ^ ((ar1 >> 1) & 3);
    const u16* Ag0 = A + (size_t)min(row0 + ar0, M - 1) * K + aq0 * 8;
    const u16* Ag1 = A + (size_t)min(row0 + ar1, M - 1) * K + aq1 * 8;
    const u16* Bg0 = Bt + (size_t)((ar0 >> 6) * Nout + col0 + (ar0 & 63)) * K + aq0 * 8;
    const u16* Bg1 = Bt + (size_t)((ar1 >> 6) * Nout + col0 + (ar1 & 63)) * K + aq1 * 8;
    u16* lA0 = As + wave * 512;
    u16* lA1 = As + 2048 + wave * 512;
    u16* lB0 = Bs + wave * 512;
    u16* lB1 = Bs + 2048 + wave * 512;
    f32x4 acc[2][2][4] = {};
    for (int k0 = 0; k0 < K; k0 += 32) {
        __syncthreads();
        glds16(Ag0 + k0, lA0);
        glds16(Ag1 + k0, lA1);
        glds16(Bg0 + k0, lB0);
        glds16(Bg1 + k0, lB1);
        __syncthreads();
        bf16x8 af[2], bv[2][4];
        #pragma unroll
        for (int i = 0; i < 2; ++i) {
            int row = wave * 32 + i * 16 + r;
            af[i] = *(const bf16x8*)(As + (row * 4 + (quad ^ ((row >> 1) & 3))) * 8);
        }
        #pragma unroll
        for (int p = 0; p < 2; ++p)
            #pragma unroll
            for (int g = 0; g < 4; ++g) {
                int row = p * 64 + g * 16 + r;
                bv[p][g] = *(const bf16x8*)(Bs + (row * 4 + (quad ^ ((row >> 1) & 3))) * 8);
            }
        #pragma unroll
        for (int p = 0; p < 2; ++p)
            #pragma unroll
            for (int i = 0; i < 2; ++i)
                #pragma unroll
                for (int g = 0; g < 4; ++g)
                    acc[p][i][g] = __builtin_amdgcn_mfma_f32_16x16x32_bf16(af[i], bv[p][g], acc[p][i][g], 0, 0, 0);
    }
    #pragma unroll
    for (int i = 0; i < 2; ++i) {
        int grow = row0 + wave * 32 + i * 16 + quad * 4;
        #pragma unroll
        for (int g = 0; g < 4; ++g) {
            int gcol = col0 + g * 16 + r;
            float bva = ldf(bias, gcol, isf32);
            float bvu = ldf(bias, Nout + gcol, isf32);
            #pragma unroll
            for (int t = 0; t < 4; ++t) {
                float a = acc[0][i][g][t] + bva;
                float u = acc[1][i][g][t] + bvu;
                // 0.5u(1+tanh z) == u * sigmoid(2z); v_exp + v_rcp instead of tanhf
                float z2 = 1.5957691216f * (u + 0.044715f * u * u * u);
                float gl = u * __builtin_amdgcn_rcpf(1.f + __expf(-z2));
                Out[(size_t)(grow + t) * Nout + gcol] = f2bf(a * gl);
            }
        }
    }
}

// ============ FALLBACK: round-4 64x64 GEMM (known-good) ============
template <int EPI, bool AEXT>
__global__ __launch_bounds__(256) void k_gemm(const void* __restrict__ A, const void* __restrict__ B,
                                              void* __restrict__ Cout, float* __restrict__ Rf,
                                              const void* __restrict__ bias,
                                              int M, int N, int K, const int* __restrict__ flagp) {
    int isf32 = *flagp;
    __shared__ u16 As[64][40];
    __shared__ u16 Bs[64][40];
    int tid = threadIdx.x;
    int row0 = blockIdx.x * 64, col0 = blockIdx.y * 64;
    int wave = tid >> 6, lane = tid & 63;
    int wm = (wave >> 1) * 32, wn = (wave & 1) * 32;
    int quad = lane >> 4, r = lane & 15;
    int arow = tid >> 2, akk = (tid & 3) * 8;
    int bnl = tid & 63, bkk = (tid >> 6) * 8;
    int garow = row0 + arow;
    f32x4 acc[2][2] = {};
    for (int k0 = 0; k0 < K; k0 += 32) {
        uint4 aval = {0u, 0u, 0u, 0u};
        if (garow < M) {
            if (AEXT && isf32) {
                const float* Af = (const float*)A;
                u16 t[8];
                #pragma unroll
                for (int j = 0; j < 8; ++j) t[j] = f2bf(Af[(size_t)garow * K + k0 + akk + j]);
                aval = *(uint4*)t;
            } else {
                aval = *(const uint4*)((const u16*)A + (size_t)garow * K + k0 + akk);
            }
        }
        u16 btmp[8];
        #pragma unroll
        for (int j = 0; j < 8; ++j) btmp[j] = ldbf(B, (size_t)(k0 + bkk + j) * N + col0 + bnl, isf32);
        __syncthreads();
        *(uint4*)(&As[arow][akk]) = aval;
        *(uint4*)(&Bs[bnl][bkk]) = *(uint4*)btmp;
        __syncthreads();
        bf16x8 a0 = *(const bf16x8*)(&As[wm + r][quad * 8]);
        bf16x8 a1 = *(const bf16x8*)(&As[wm + 16 + r][quad * 8]);
        bf16x8 b0 = *(const bf16x8*)(&Bs[wn + r][quad * 8]);
        bf16x8 b1 = *(const bf16x8*)(&Bs[wn + 16 + r][quad * 8]);
        acc[0][0] = __builtin_amdgcn_mfma_f32_16x16x32_bf16(a0, b0, acc[0][0], 0, 0, 0);
        acc[0][1] = __builtin_amdgcn_mfma_f32_16x16x32_bf16(a0, b1, acc[0][1], 0, 0, 0);
        acc[1][0] = __builtin_amdgcn_mfma_f32_16x16x32_bf16(a1, b0, acc[1][0], 0, 0, 0);
        acc[1][1] = __builtin_amdgcn_mfma_f32_16x16x32_bf16(a1, b1, acc[1][1], 0, 0, 0);
    }
    #pragma unroll
    for (int i = 0; i < 2; ++i)
        #pragma unroll
        for (int jn = 0; jn < 2; ++jn)
            #pragma unroll
            for (int t = 0; t < 4; ++t) {
                int grow = row0 + wm + i * 16 + quad * 4 + t;
                int gcol = col0 + wn + jn * 16 + r;
                if (grow >= M) continue;
                float v = acc[i][jn][t];
                size_t off = (size_t)grow * N + gcol;
                if (EPI == 0) {
                    ((u16*)Cout)[off] = f2bf(v);
                } else if (EPI == 2) {
                    Rf[off] += v + ldf(bias, gcol, isf32);
                } else {
                    ((float*)Cout)[off] = v + ldf(bias, gcol, isf32) + Rf[off];
                }
            }
}

// ============ FALLBACK: round-4 geglu ============
__global__ __launch_bounds__(256) void k_gemm_geglu(const u16* __restrict__ A, const void* __restrict__ B,
                                                    const void* __restrict__ bias, u16* __restrict__ Out,
                                                    int M, int Nout, int K, int ldb,
                                                    const int* __restrict__ flagp) {
    int isf32 = *flagp;
    __shared__ u16 As[64][40];
    __shared__ u16 Bs[64][40];
    int tid = threadIdx.x;
    int row0 = blockIdx.x * 64, col0 = blockIdx.y * 64;
    int wave = tid >> 6, lane = tid & 63;
    int wm = (wave >> 1) * 32, wn = (wave & 1) * 32;
    int quad = lane >> 4, r = lane & 15;
    int arow = tid >> 2, akk = (tid & 3) * 8;
    int bnl = tid & 63, bkk = (tid >> 6) * 8;
    int garow = row0 + arow;
    f32x4 acc[2][2][2] = {};
    for (int p = 0; p < 2; ++p) {
        for (int k0 = 0; k0 < K; k0 += 32) {
            uint4 aval = {0u, 0u, 0u, 0u};
            if (garow < M) aval = *(const uint4*)(A + (size_t)garow * K + k0 + akk);
            u16 btmp[8];
            #pragma unroll
            for (int j = 0; j < 8; ++j)
                btmp[j] = ldbf(B, (size_t)(k0 + bkk + j) * ldb + p * Nout + col0 + bnl, isf32);
            __syncthreads();
            *(uint4*)(&As[arow][akk]) = aval;
            *(uint4*)(&Bs[bnl][bkk]) = *(uint4*)btmp;
            __syncthreads();
            bf16x8 a0 = *(const bf16x8*)(&As[wm + r][quad * 8]);
            bf16x8 a1 = *(const bf16x8*)(&As[wm + 16 + r][quad * 8]);
            bf16x8 b0 = *(const bf16x8*)(&Bs[wn + r][quad * 8]);
            bf16x8 b1 = *(const bf16x8*)(&Bs[wn + 16 + r][quad * 8]);
            acc[p][0][0] = __builtin_amdgcn_mfma_f32_16x16x32_bf16(a0, b0, acc[p][0][0], 0, 0, 0);
            acc[p][0][1] = __builtin_amdgcn_mfma_f32_16x16x32_bf16(a0, b1, acc[p][0][1], 0, 0, 0);
            acc[p][1][0] = __builtin_amdgcn_mfma_f32_16x16x32_bf16(a1, b0, acc[p][1][0], 0, 0, 0);
            acc[p][1][1] = __builtin_amdgcn_mfma_f32_16x16x32_bf16(a1, b1, acc[p][1][1], 0, 0, 0);
        }
    }
    #pragma unroll
    for (int i = 0; i < 2; ++i)
        #pragma unroll
        for (int jn = 0; jn < 2; ++jn)
            #pragma unroll
            for (int t = 0; t < 4; ++t) {
                int grow = row0 + wm + i * 16 + quad * 4 + t;
                int gcol = col0 + wn + jn * 16 + r;
                if (grow >= M) continue;
                float a = acc[0][i][jn][t] + ldf(bias, gcol, isf32);
                float u = acc[1][i][jn][t] + ldf(bias, Nout + gcol, isf32);
                float th = tanhf(0.7978845608f * (u + 0.044715f * u * u * u));
                float gl = 0.5f * u * (1.f + th);
                Out[(size_t)grow * Nout + gcol] = f2bf(a * gl);
            }
}

// ---------------- MFMA flash attention (parameterized strides) ----------------
__global__ __launch_bounds__(256) void k_attn_flash(const u16* __restrict__ Q, const u16* __restrict__ K,
                                                    const u16* __restrict__ V, u16* __restrict__ O,
                                                    int N, int Mkv, int H, int ldq, int ldkv, int ldo) {
    __shared__ u16 Sp[4][16][40];
    __shared__ u16 VT[64][40];
    int nt = N / 64;
    int qt = blockIdx.x % nt;
    int bh = blockIdx.x / nt;
    int h = bh % H, b = bh / H;
    int tid = threadIdx.x, wave = tid >> 6, lane = tid & 63;
    int quad = lane >> 4, r = lane & 15;
    int q0 = qt * 64 + wave * 16;

    const u16* qbase = Q + ((size_t)(b * N + q0 + r)) * ldq + h * 64;
    bf16x8 aq0 = *(const bf16x8*)(qbase + quad * 8);
    bf16x8 aq1 = *(const bf16x8*)(qbase + 32 + quad * 8);

    f32x4 accO[4] = {};
    float m_i[4] = {-1e30f, -1e30f, -1e30f, -1e30f};
    float l_i[4] = {0.f, 0.f, 0.f, 0.f};

    int vkv = tid & 31, vdg = tid >> 5;

    for (int kv0 = 0; kv0 < Mkv; kv0 += 32) {
        int kr0 = min(kv0 + r, Mkv - 1);
        int kr1 = min(kv0 + 16 + r, Mkv - 1);
        const u16* kb0 = K + ((size_t)(b * Mkv + kr0)) * ldkv + h * 64;
        const u16* kb1 = K + ((size_t)(b * Mkv + kr1)) * ldkv + h * 64;
        bf16x8 bk00 = *(const bf16x8*)(kb0 + quad * 8);
        bf16x8 bk01 = *(const bf16x8*)(kb0 + 32 + quad * 8);
        bf16x8 bk10 = *(const bf16x8*)(kb1 + quad * 8);
        bf16x8 bk11 = *(const bf16x8*)(kb1 + 32 + quad * 8);
        int vrow = min(kv0 + vkv, Mkv - 1);
        uint4 vv = *(const uint4*)(V + ((size_t)(b * Mkv + vrow)) * ldkv + h * 64 + vdg * 8);

        __syncthreads();
        VT[vdg * 8 + 0][vkv] = (u16)(vv.x);
        VT[vdg * 8 + 1][vkv] = (u16)(vv.x >> 16);
        VT[vdg * 8 + 2][vkv] = (u16)(vv.y);
        VT[vdg * 8 + 3][vkv] = (u16)(vv.y >> 16);
        VT[vdg * 8 + 4][vkv] = (u16)(vv.z);
        VT[vdg * 8 + 5][vkv] = (u16)(vv.z >> 16);
        VT[vdg * 8 + 6][vkv] = (u16)(vv.w);
        VT[vdg * 8 + 7][vkv] = (u16)(vv.w >> 16);
        __syncthreads();

        f32x4 s0 = {}, s1 = {};
        s0 = __builtin_amdgcn_mfma_f32_16x16x32_bf16(aq0, bk00, s0, 0, 0, 0);
        s0 = __builtin_amdgcn_mfma_f32_16x16x32_bf16(aq1, bk01, s0, 0, 0, 0);
        s1 = __builtin_amdgcn_mfma_f32_16x16x32_bf16(aq0, bk10, s1, 0, 0, 0);
        s1 = __builtin_amdgcn_mfma_f32_16x16x32_bf16(aq1, bk11, s1, 0, 0, 0);
        bool mask0 = (kv0 + r) >= Mkv;
        bool mask1 = (kv0 + 16 + r) >= Mkv;

        #pragma unroll
        for (int t = 0; t < 4; ++t) {
            float a = mask0 ? -1e30f : s0[t] * 0.125f;
            float c = mask1 ? -1e30f : s1[t] * 0.125f;
            float mx = fmaxf(a, c);
            mx = fmaxf(mx, __shfl_xor(mx, 1));
            mx = fmaxf(mx, __shfl_xor(mx, 2));
            mx = fmaxf(mx, __shfl_xor(mx, 4));
            mx = fmaxf(mx, __shfl_xor(mx, 8));
            float mn = fmaxf(m_i[t], mx);
            float alpha = __expf(m_i[t] - mn);
            float p0 = __expf(a - mn);
            float p1 = __expf(c - mn);
            float ps = p0 + p1;
            ps += __shfl_xor(ps, 1);
            ps += __shfl_xor(ps, 2);
            ps += __shfl_xor(ps, 4);
            ps += __shfl_xor(ps, 8);
            l_i[t] = l_i[t] * alpha + ps;
            m_i[t] = mn;
            accO[0][t] *= alpha; accO[1][t] *= alpha; accO[2][t] *= alpha; accO[3][t] *= alpha;
            Sp[wave][quad * 4 + t][r] = f2bf(p0);
            Sp[wave][quad * 4 + t][16 + r] = f2bf(p1);
        }

        bf16x8 ap = *(const bf16x8*)(&Sp[wave][r][quad * 8]);
        #pragma unroll
        for (int g = 0; g < 4; ++g) {
            bf16x8 bvv = *(const bf16x8*)(&VT[g * 16 + r][quad * 8]);
            accO[g] = __builtin_amdgcn_mfma_f32_16x16x32_bf16(ap, bvv, accO[g], 0, 0, 0);
        }
    }

    u16* ob = O + ((size_t)(b * N + q0)) * ldo + h * 64;
    #pragma unroll
    for (int t = 0; t < 4; ++t) {
        float inv = 1.f / l_i[t];
        #pragma unroll
        for (int g = 0; g < 4; ++g)
            ob[(size_t)(quad * 4 + t) * ldo + g * 16 + r] = f2bf(accO[g][t] * inv);
    }
}

extern "C" void kernel_launch(void* const* d_in, const int* in_sizes, int n_in,
                              void* d_out, int out_size, void* d_ws, size_t ws_size,
                              hipStream_t stream) {
    const void* x    = d_in[0];
    const void* ctx  = d_in[1];
    const void* g1   = d_in[2];
    const void* be1  = d_in[3];
    const void* wq1  = d_in[4];
    const void* wk1  = d_in[5];
    const void* wv1  = d_in[6];
    const void* wo1  = d_in[7];
    const void* bo1  = d_in[8];
    const void* g2   = d_in[9];
    const void* be2  = d_in[10];
    const void* wq2  = d_in[11];
    const void* wk2  = d_in[12];
    const void* wv2  = d_in[13];
    const void* wo2  = d_in[14];
    const void* bo2  = d_in[15];
    const void* g3   = d_in[16];
    const void* be3  = d_in[17];
    const void* wff1 = d_in[18];
    const void* bff1 = d_in[19];
    const void* wff2 = d_in[20];
    const void* bff2 = d_in[21];

    const int BT = 4096, D = 1280;
    dim3 blk(256);
    char* ws = (char*)d_ws;

    const size_t NEED_FAST = 117393664;
    if (ws_size >= NEED_FAST) {
        // ---------- fast path ----------
        int*   flag   = (int*)(ws);
        u16* lnout    = (u16*)(ws + 256);            // 4096x1280 bf16
        u16* qkv      = (u16*)(ws + 10486016);       // 4096x3840 bf16 (region R)
        u16* attnout  = (u16*)(ws + 10486016 + 31457280);
        u16* gbuf     = (u16*)(ws + 10486016);       // 4096x5120 bf16, aliases qkv+attnout
        u16* ctxb     = (u16*)(ws + 52429056);       // 308x768 bf16
        u16* kv2      = (u16*)(ws + 52902144);       // 308x2560 bf16
        u16* wqkv1t   = (u16*)(ws + 54479104);       // [3840][1280]
        u16* wo1t     = (u16*)(ws + 64309504);       // [1280][1280]
        u16* wq2t     = (u16*)(ws + 67586304);
        u16* wkv2t    = (u16*)(ws + 70863104);       // [2560][768]
        u16* wo2t     = (u16*)(ws + 74795264);
        u16* wff1t    = (u16*)(ws + 78072064);       // [10240][1280]
        u16* wff2t    = (u16*)(ws + 104286464);      // [1280][5120]
        float* xres   = (float*)d_out;               // residual lives in the fp32 output

        k_detect<<<dim3(1), blk, 0, stream>>>((const u16*)x, flag);
        k_b2f<<<dim3((BT * D + 255) / 256), blk, 0, stream>>>(x, xres, BT * D, flag);
        // weight transposes (once per launch)
        k_transpose<<<dim3(40, 40), blk, 0, stream>>>(wq1, wqkv1t, 1280, 1280, flag);
        k_transpose<<<dim3(40, 40), blk, 0, stream>>>(wk1, wqkv1t + 1280 * 1280, 1280, 1280, flag);
        k_transpose<<<dim3(40, 40), blk, 0, stream>>>(wv1, wqkv1t + 2 * 1280 * 1280, 1280, 1280, flag);
        k_transpose<<<dim3(40, 40), blk, 0, stream>>>(wo1, wo1t, 1280, 1280, flag);
        k_transpose<<<dim3(40, 40), blk, 0, stream>>>(wq2, wq2t, 1280, 1280, flag);
        k_transpose<<<dim3(24, 40), blk, 0, stream>>>(wk2, wkv2t, 768, 1280, flag);
        k_transpose<<<dim3(24, 40), blk, 0, stream>>>(wv2, wkv2t + 1280 * 768, 768, 1280, flag);
        k_transpose<<<dim3(40, 40), blk, 0, stream>>>(wo2, wo2t, 1280, 1280, flag);
        k_transpose<<<dim3(40, 320), blk, 0, stream>>>(wff1, wff1t, 1280, 10240, flag);
        k_transpose<<<dim3(160, 40), blk, 0, stream>>>(wff2, wff2t, 5120, 1280, flag);
        k_cvt<<<dim3((308 * 768 + 255) / 256), blk, 0, stream>>>(ctx, ctxb, 308 * 768, flag);
        // --- self attention ---
        k_layernorm<<<dim3(BT), blk, 0, stream>>>(xres, g1, be1, lnout, D, flag);
        k_gemm_t<0><<<dim3(32, 30), blk, 0, stream>>>(lnout, wqkv1t, qkv, nullptr, nullptr, BT, 3840, D, flag);
        k_attn_flash<<<dim3(16 * 80), blk, 0, stream>>>(qkv, qkv + 1280, qkv + 2560, attnout,
                                                        1024, 1024, 20, 3840, 3840, 1280);
        k_gemm_t<2><<<dim3(32, 10), blk, 0, stream>>>(attnout, wo1t, nullptr, xres, bo1, BT, D, D, flag);
        // --- cross attention ---
        k_layernorm<<<dim3(BT), blk, 0, stream>>>(xres, g2, be2, lnout, D, flag);
        k_gemm_t<0><<<dim3(32, 10), blk, 0, stream>>>(lnout, wq2t, qkv, nullptr, nullptr, BT, D, D, flag);
        k_gemm_t<0><<<dim3(3, 20), blk, 0, stream>>>(ctxb, wkv2t, kv2, nullptr, nullptr, 308, 2560, 768, flag);
        k_attn_flash<<<dim3(16 * 80), blk, 0, stream>>>(qkv, kv2, kv2 + 1280, attnout,
                                                        1024, 77, 20, 1280, 2560, 1280);
        k_gemm_t<2><<<dim3(32, 10), blk, 0, stream>>>(attnout, wo2t, nullptr, xres, bo2, BT, D, D, flag);
        // --- GEGLU FF ---
        k_layernorm<<<dim3(BT), blk, 0, stream>>>(xres, g3, be3, lnout, D, flag);
        k_geglu_t<<<dim3(32, 80), blk, 0, stream>>>(lnout, wff1t, bff1, gbuf, BT, D, flag);
        k_gemm_t<2><<<dim3(32, 10), blk, 0, stream>>>(gbuf, wff2t, nullptr, xres, bff2, BT, D, 5120, flag);
    } else {
        // ---------- fallback: round-4 path (known-good, ~75 MB ws) ----------
        int*   flag    = (int*)(ws);
        float* xres    = (float*)(ws + 256);
        u16* lnout     = (u16*)(ws + 20971776);
        u16* q         = (u16*)(ws + 31457536);
        u16* kbuf      = (u16*)(ws + 41943296);
        u16* vbuf      = (u16*)(ws + 52429056);
        u16* attnout   = (u16*)(ws + 62914816);
        u16* k2        = (u16*)(ws + 73400576);
        u16* v2        = (u16*)(ws + 74189056);
        u16* gbuf      = (u16*)(ws + 31457536);

        dim3 g_gemm(64, 20);
        dim3 g_kv(5, 20);
        dim3 g_attn(16 * 80);

        k_detect<<<dim3(1), blk, 0, stream>>>((const u16*)x, flag);
        k_b2f<<<dim3((BT * D + 255) / 256), blk, 0, stream>>>(x, xres, BT * D, flag);
        k_layernorm<<<dim3(BT), blk, 0, stream>>>(xres, g1, be1, lnout, D, flag);
        k_gemm<0, false><<<g_gemm, blk, 0, stream>>>(lnout, wq1, q, nullptr, nullptr, BT, D, D, flag);
        k_gemm<0, false><<<g_gemm, blk, 0, stream>>>(lnout, wk1, kbuf, nullptr, nullptr, BT, D, D, flag);
        k_gemm<0, false><<<g_gemm, blk, 0, stream>>>(lnout, wv1, vbuf, nullptr, nullptr, BT, D, D, flag);
        k_attn_flash<<<g_attn, blk, 0, stream>>>(q, kbuf, vbuf, attnout, 1024, 1024, 20, 1280, 1280, 1280);
        k_gemm<2, false><<<g_gemm, blk, 0, stream>>>(attnout, wo1, nullptr, xres, bo1, BT, D, D, flag);
        k_layernorm<<<dim3(BT), blk, 0, stream>>>(xres, g2, be2, lnout, D, flag);
        k_gemm<0, false><<<g_gemm, blk, 0, stream>>>(lnout, wq2, q, nullptr, nullptr, BT, D, D, flag);
        k_gemm<0, true><<<g_kv, blk, 0, stream>>>(ctx, wk2, k2, nullptr, nullptr, 308, D, 768, flag);
        k_gemm<0, true><<<g_kv, blk, 0, stream>>>(ctx, wv2, v2, nullptr, nullptr, 308, D, 768, flag);
        k_attn_flash<<<g_attn, blk, 0, stream>>>(q, k2, v2, attnout, 1024, 77, 20, 1280, 1280, 1280);
        k_gemm<2, false><<<g_gemm, blk, 0, stream>>>(attnout, wo2, nullptr, xres, bo2, BT, D, D, flag);
        k_layernorm<<<dim3(BT), blk, 0, stream>>>(xres, g3, be3, lnout, D, flag);
        k_gemm_geglu<<<dim3(64, 80), blk, 0, stream>>>(lnout, wff1, bff1, gbuf, BT, 5120, D, 10240, flag);
        k_gemm<3, false><<<g_gemm, blk, 0, stream>>>(gbuf, wff2, d_out, xres, bff2, BT, D, 5120, flag);
    }
}